// Round 1
// baseline (13337.737 us; speedup 1.0000x reference)
//
#include <hip/hip_runtime.h>
#include <stdint.h>

#define TSEQ 512
#define NB   64
#define EMB  300
#define HID  300
#define G4   1200
#define KKP  150     // pairs of K (300/2)
#define NT   9
#define MTOT (TSEQ*NB)   // 32768

typedef _Float16 h2v __attribute__((ext_vector_type(2)));
union H2U { uint32_t u; h2v h; };

__device__ __forceinline__ float dot2f(uint32_t a, uint32_t b, float c) {
#if __has_builtin(__builtin_amdgcn_fdot2)
  H2U ua; ua.u = a; H2U ub; ub.u = b;
  return __builtin_amdgcn_fdot2(ua.h, ub.h, c, false);
#else
  H2U ua; ua.u = a; H2U ub; ub.u = b;
  return c + (float)ua.h.x*(float)ub.h.x + (float)ua.h.y*(float)ub.h.y;
#endif
}

__device__ __forceinline__ uint32_t packf2(float a, float b) {
  H2U u; u.h.x = (_Float16)a; u.h.y = (_Float16)b; return u.u;
}

__device__ __forceinline__ float sigm(float x) { return 1.0f / (1.0f + expf(-x)); }

// ---- pack W_ih / W_hh (all [1200][300] f32) into f16x2 [150][1200] ----
__global__ __launch_bounds__(256) void prep_w(
    const float* __restrict__ Wihf, const float* __restrict__ Wihb,
    const float* __restrict__ Whhf, const float* __restrict__ Whhb,
    uint32_t* __restrict__ wtih, uint32_t* __restrict__ wthh) {
  int i = blockIdx.x * 256 + threadIdx.x;
  if (i >= KKP * G4) return;
  int m = blockIdx.y;  // 0:ih_f 1:ih_b 2:hh_f 3:hh_b
  int kk = i / G4, g = i % G4;
  const float* src = (m == 0) ? Wihf : (m == 1) ? Wihb : (m == 2) ? Whhf : Whhb;
  float2 v = *(const float2*)(src + (size_t)g * 300 + 2 * kk);
  uint32_t u = packf2(v.x, v.y);
  if (m < 2) wtih[(size_t)m * (KKP * G4) + i] = u;
  else       wthh[(size_t)(m - 2) * (KKP * G4) + i] = u;
}

__global__ __launch_bounds__(256) void prep_bias(
    const float* __restrict__ bihf, const float* __restrict__ bhhf,
    const float* __restrict__ bihb, const float* __restrict__ bhhb,
    float* __restrict__ bias) {
  int i = blockIdx.x * 256 + threadIdx.x;
  if (i < G4) {
    bias[i]       = bihf[i] + bhhf[i];
    bias[G4 + i]  = bihb[i] + bhhb[i];
  }
}

// ---- gather embeddings -> packed f16x2, layout Ae[kk][m] (m = t*64+b) ----
__global__ __launch_bounds__(256) void gather_emb(
    const int* __restrict__ x, const float* __restrict__ emb,
    uint32_t* __restrict__ Ae) {
  __shared__ __align__(16) uint32_t buf[64 * KKP];
  __shared__ int idxs[64];
  int tid = threadIdx.x;
  int m0 = blockIdx.x * 64;
  if (tid < 64) {
    int mm = m0 + tid;
    idxs[tid] = x[(size_t)(mm & 63) * TSEQ + (mm >> 6)];   // x[b][t]
  }
  __syncthreads();
  for (int i = tid; i < 64 * KKP; i += 256) {
    int mm = i / KKP, kk = i % KKP;
    float2 v = *(const float2*)(emb + (size_t)idxs[mm] * EMB + 2 * kk);
    buf[i] = packf2(v.x, v.y);
  }
  __syncthreads();
  for (int i = tid; i < 64 * KKP; i += 256) {
    int kk = i >> 6, mm = i & 63;
    Ae[(size_t)kk * MTOT + m0 + mm] = buf[mm * KKP + kk];
  }
}

// ---- pre = emb @ W_ih^T + (b_ih+b_hh), stored f16 [2][32768][1200] ----
__global__ __launch_bounds__(256) void embed_pre(
    const uint32_t* __restrict__ Ae, const uint32_t* __restrict__ wtih,
    const float* __restrict__ bias, _Float16* __restrict__ pre) {
  int d = blockIdx.z;
  int m0 = blockIdx.x * 64, n0 = blockIdx.y * 64;
  int tid = threadIdx.x;
  __shared__ __align__(16) uint32_t As[30 * 64];
  __shared__ __align__(16) uint32_t Bs[30 * 64];
  const uint32_t* W = wtih + (size_t)d * (KKP * G4);
  int tx = tid & 15, ty = tid >> 4;
  float acc[4][4] = {};
  for (int c = 0; c < 5; ++c) {
    int kb = c * 30;
    for (int i = tid; i < 30 * 64; i += 256) {
      int kk = i >> 6, mm = i & 63;
      As[i] = Ae[(size_t)(kb + kk) * MTOT + m0 + mm];
    }
    for (int i = tid; i < 30 * 64; i += 256) {
      int kk = i >> 6, cc = i & 63;
      int g = n0 + cc;
      Bs[i] = (g < G4) ? W[(size_t)(kb + kk) * G4 + g] : 0u;
    }
    __syncthreads();
    #pragma unroll 5
    for (int kk = 0; kk < 30; ++kk) {
      uint4 a4 = *(const uint4*)&As[kk * 64 + ty * 4];
      uint4 b4 = *(const uint4*)&Bs[kk * 64 + tx * 4];
      uint32_t av[4] = {a4.x, a4.y, a4.z, a4.w};
      uint32_t bv[4] = {b4.x, b4.y, b4.z, b4.w};
      #pragma unroll
      for (int im = 0; im < 4; ++im)
        #pragma unroll
        for (int in = 0; in < 4; ++in)
          acc[im][in] = dot2f(av[im], bv[in], acc[im][in]);
    }
    __syncthreads();
  }
  #pragma unroll
  for (int im = 0; im < 4; ++im) {
    int mm = m0 + ty * 4 + im;
    #pragma unroll
    for (int in = 0; in < 4; ++in) {
      int g = n0 + tx * 4 + in;
      if (g < G4)
        pre[((size_t)d * MTOT + mm) * G4 + g] = (_Float16)(acc[im][in] + bias[d * G4 + g]);
    }
  }
}

// ---- the sequential LSTM: one workgroup per (dir, batch) chain ----
__global__ __launch_bounds__(256) void lstm(
    const uint32_t* __restrict__ wthh, const _Float16* __restrict__ pre,
    float* __restrict__ hs) {
  int d = blockIdx.x >> 6;
  int b = blockIdx.x & 63;
  int tid = threadIdx.x;
  __shared__ uint32_t h2s[KKP];
  __shared__ float cs[HID];
  __shared__ float gate[G4];
  for (int i = tid; i < KKP; i += 256) h2s[i] = 0u;
  for (int i = tid; i < HID; i += 256) cs[i] = 0.0f;
  __syncthreads();
  const uint32_t* Wd = wthh + (size_t)d * (KKP * G4);
  const bool has5 = tid < (G4 - 1024);   // tid < 176
  for (int s = 0; s < TSEQ; ++s) {
    int t = d ? (TSEQ - 1 - s) : s;
    const _Float16* prow = pre + ((size_t)d * MTOT + (size_t)t * NB + b) * G4;
    float acc0 = 0.f, acc1 = 0.f, acc2 = 0.f, acc3 = 0.f, acc4 = 0.f;
    for (int kk = 0; kk < KKP; ++kk) {
      uint32_t hv = h2s[kk];
      const uint32_t* wrow = Wd + (size_t)kk * G4 + tid;
      acc0 = dot2f(wrow[0],    hv, acc0);
      acc1 = dot2f(wrow[256],  hv, acc1);
      acc2 = dot2f(wrow[512],  hv, acc2);
      acc3 = dot2f(wrow[768],  hv, acc3);
      if (has5) acc4 = dot2f(wrow[1024], hv, acc4);
    }
    gate[tid]        = acc0 + (float)prow[tid];
    gate[tid + 256]  = acc1 + (float)prow[tid + 256];
    gate[tid + 512]  = acc2 + (float)prow[tid + 512];
    gate[tid + 768]  = acc3 + (float)prow[tid + 768];
    if (has5) gate[tid + 1024] = acc4 + (float)prow[tid + 1024];
    __syncthreads();
    if (tid < KKP) {
      int j0 = 2 * tid;
      float i0 = sigm(gate[j0]),     f0 = sigm(gate[HID + j0]);
      float g0 = tanhf(gate[2*HID + j0]), o0 = sigm(gate[3*HID + j0]);
      float i1 = sigm(gate[j0+1]),   f1 = sigm(gate[HID + j0+1]);
      float g1 = tanhf(gate[2*HID + j0+1]), o1 = sigm(gate[3*HID + j0+1]);
      float c0 = f0 * cs[j0]   + i0 * g0; cs[j0]   = c0;
      float c1 = f1 * cs[j0+1] + i1 * g1; cs[j0+1] = c1;
      float hh0 = o0 * tanhf(c0), hh1 = o1 * tanhf(c1);
      h2s[tid] = packf2(hh0, hh1);
      float* hrow = hs + ((size_t)d * MTOT + (size_t)t * NB + b) * HID;
      float2 hw; hw.x = hh0; hw.y = hh1;
      *(float2*)(hrow + j0) = hw;
    }
    __syncthreads();
  }
}

// ---- logits = [h_f,h_b] @ W_lin^T + b_lin ; probs = softmax ----
__global__ __launch_bounds__(256) void logits_probs(
    const float* __restrict__ hs, const float* __restrict__ Wlin,
    const float* __restrict__ blin, float* __restrict__ probs) {
  __shared__ float Ws[NT * 600];
  __shared__ float bs[NT];
  int tid = threadIdx.x;
  for (int i = tid; i < NT * 600; i += 256) Ws[i] = Wlin[i];
  if (tid < NT) bs[tid] = blin[tid];
  __syncthreads();
  int wave = tid >> 6, lane = tid & 63;
  int tb = blockIdx.x * 4 + wave;     // = t*64 + b
  const float* hf = hs + (size_t)tb * HID;
  const float* hb = hs + ((size_t)MTOT + tb) * HID;
  float p[NT];
  #pragma unroll
  for (int k = 0; k < NT; ++k) p[k] = 0.f;
  for (int e = lane; e < HID; e += 64) {
    float vf = hf[e], vb = hb[e];
    #pragma unroll
    for (int k = 0; k < NT; ++k)
      p[k] += vf * Ws[k * 600 + e] + vb * Ws[k * 600 + 300 + e];
  }
  #pragma unroll
  for (int off = 32; off > 0; off >>= 1)
    #pragma unroll
    for (int k = 0; k < NT; ++k) p[k] += __shfl_xor(p[k], off);
  float l[NT]; float mx = -1e30f;
  #pragma unroll
  for (int k = 0; k < NT; ++k) { l[k] = p[k] + bs[k]; mx = fmaxf(mx, l[k]); }
  float ssum = 0.f;
  #pragma unroll
  for (int k = 0; k < NT; ++k) ssum = ssum + expf(l[k] - mx);
  int t = tb >> 6, b = tb & 63;
  if (lane < NT)
    probs[((size_t)b * TSEQ + t) * NT + lane] = expf(l[lane] - mx) / ssum;
}

// ---- CRF numerator per batch ----
__global__ __launch_bounds__(256) void crf_num(
    const int* __restrict__ y, const float* __restrict__ probs,
    const float* __restrict__ strt, const float* __restrict__ endt,
    const float* __restrict__ trans, float* __restrict__ nums) {
  int b = blockIdx.x, tid = threadIdx.x;
  __shared__ float r1[256], r2[256];
  float s = 0.f, cnt = 0.f;
  for (int t = tid; t < TSEQ; t += 256) {
    int yc = y[(size_t)b * TSEQ + t];
    cnt += (yc != -1) ? 1.f : 0.f;
    if (t >= 1) {
      int yp = y[(size_t)b * TSEQ + t - 1];
      float mask = (yc != -1) ? 1.f : 0.f;
      s += mask * (trans[yp * NT + yc] + probs[((size_t)b * TSEQ + t) * NT + yc]);
    }
  }
  r1[tid] = s; r2[tid] = cnt;
  __syncthreads();
  for (int off = 128; off > 0; off >>= 1) {
    if (tid < off) { r1[tid] += r1[tid + off]; r2[tid] += r2[tid + off]; }
    __syncthreads();
  }
  if (tid == 0) {
    int y0 = y[(size_t)b * TSEQ];
    int seqlen = (int)(r2[0] + 0.5f);
    int ylast = y[(size_t)b * TSEQ + seqlen - 1];
    nums[b] = strt[y0] + probs[((size_t)b * TSEQ) * NT + y0] + r1[0] + endt[ylast];
  }
}

// ---- CRF forward algorithm (denominator) per batch ----
__global__ __launch_bounds__(64) void crf_alpha(
    const int* __restrict__ y, const float* __restrict__ probs,
    const float* __restrict__ strt, const float* __restrict__ endt,
    const float* __restrict__ trans, float* __restrict__ dens) {
  int b = blockIdx.x, lane = threadIdx.x;
  __shared__ float tr[NT * NT];
  __shared__ float al[NT];
  if (lane < NT * NT) tr[lane] = trans[lane];
  if (lane < NT) al[lane] = strt[lane] + probs[((size_t)b * TSEQ) * NT + lane];
  __syncthreads();
  for (int t = 1; t < TSEQ; ++t) {
    float nxt = 0.f;
    int m = (y[(size_t)b * TSEQ + t] != -1);
    if (lane < NT) {
      float e = probs[((size_t)b * TSEQ + t) * NT + lane];
      float mx = -1e30f;
      #pragma unroll
      for (int j = 0; j < NT; ++j) mx = fmaxf(mx, al[j] + tr[j * NT + lane]);
      float sum = 0.f;
      #pragma unroll
      for (int j = 0; j < NT; ++j) sum += expf(al[j] + tr[j * NT + lane] - mx);
      nxt = e + mx + logf(sum);
    }
    __syncthreads();
    if (lane < NT && m) al[lane] = nxt;
    __syncthreads();
  }
  if (lane == 0) {
    float mx = -1e30f;
    for (int k = 0; k < NT; ++k) mx = fmaxf(mx, al[k] + endt[k]);
    float sum = 0.f;
    for (int k = 0; k < NT; ++k) sum += expf(al[k] + endt[k] - mx);
    dens[b] = mx + logf(sum);
  }
}

__global__ __launch_bounds__(64) void final_sum(
    const float* __restrict__ nums, const float* __restrict__ dens,
    float* __restrict__ out) {
  __shared__ float r[64];
  int tid = threadIdx.x;
  r[tid] = nums[tid] - dens[tid];
  __syncthreads();
  for (int off = 32; off > 0; off >>= 1) {
    if (tid < off) r[tid] += r[tid + off];
    __syncthreads();
  }
  if (tid == 0) out[(size_t)MTOT * NT] = -r[0];
}

extern "C" void kernel_launch(void* const* d_in, const int* in_sizes, int n_in,
                              void* d_out, int out_size, void* d_ws, size_t ws_size,
                              hipStream_t stream) {
  (void)in_sizes; (void)n_in; (void)out_size;
  const int*   x     = (const int*)d_in[0];
  const int*   y     = (const int*)d_in[1];
  const float* emb   = (const float*)d_in[2];
  const float* Wihf  = (const float*)d_in[3];
  const float* Whhf  = (const float*)d_in[4];
  const float* bihf  = (const float*)d_in[5];
  const float* bhhf  = (const float*)d_in[6];
  const float* Wihb  = (const float*)d_in[7];
  const float* Whhb  = (const float*)d_in[8];
  const float* bihb  = (const float*)d_in[9];
  const float* bhhb  = (const float*)d_in[10];
  const float* Wlin  = (const float*)d_in[11];
  const float* blin  = (const float*)d_in[12];
  const float* strt  = (const float*)d_in[13];
  const float* endt  = (const float*)d_in[14];
  const float* trans = (const float*)d_in[15];
  float* outp = (float*)d_out;

  char* ws = (char*)d_ws;
  const size_t OFF_WTIH = 0;                   // 1,440,000 B
  const size_t OFF_WTHH = 1440000;             // 1,440,000 B
  const size_t OFF_BIAS = 2880000;             // 9,600 B
  const size_t OFF_NUMS = 2889600;             // 256 B
  const size_t OFF_DENS = 2889856;             // 256 B
  const size_t OFF_AE   = 2890240;             // 19,660,800 B
  const size_t OFF_HS   = 22551040;            // 78,643,200 B
  const size_t OFF_PRE  = 101194240;           // 157,286,400 B -> end 258,480,640
  if (ws_size < 258480640ull) return;

  uint32_t* wtih = (uint32_t*)(ws + OFF_WTIH);
  uint32_t* wthh = (uint32_t*)(ws + OFF_WTHH);
  float*    bias = (float*)(ws + OFF_BIAS);
  float*    nums = (float*)(ws + OFF_NUMS);
  float*    dens = (float*)(ws + OFF_DENS);
  uint32_t* Ae   = (uint32_t*)(ws + OFF_AE);
  float*    hsb  = (float*)(ws + OFF_HS);
  _Float16* pre  = (_Float16*)(ws + OFF_PRE);

  prep_w<<<dim3((KKP * G4 + 255) / 256, 4), 256, 0, stream>>>(Wihf, Wihb, Whhf, Whhb, wtih, wthh);
  prep_bias<<<dim3((G4 + 255) / 256), 256, 0, stream>>>(bihf, bhhf, bihb, bhhb, bias);
  gather_emb<<<dim3(MTOT / 64), 256, 0, stream>>>(x, emb, Ae);
  embed_pre<<<dim3(MTOT / 64, (G4 + 63) / 64, 2), 256, 0, stream>>>(Ae, wtih, bias, pre);
  lstm<<<dim3(128), 256, 0, stream>>>(wthh, pre, hsb);
  logits_probs<<<dim3(MTOT / 4), 256, 0, stream>>>(hsb, Wlin, blin, outp);
  crf_num<<<dim3(NB), 256, 0, stream>>>(y, outp, strt, endt, trans, nums);
  crf_alpha<<<dim3(NB), 64, 0, stream>>>(y, outp, strt, endt, trans, dens);
  final_sum<<<1, 64, 0, stream>>>(nums, dens, outp);
}

// Round 2
// 5927.702 us; speedup vs baseline: 2.2501x; 2.2501x over previous
//
#include <hip/hip_runtime.h>
#include <stdint.h>

#define TSEQ 512
#define NB   64
#define EMB  300
#define HID  300
#define G4   1200
#define KKP  150     // pairs of K (300/2)
#define KKP2 152     // padded to multiple of 4 for uint4 unroll
#define NT   9
#define MTOT (TSEQ*NB)   // 32768

typedef _Float16 h2v __attribute__((ext_vector_type(2)));
union H2U { uint32_t u; h2v h; };

__device__ __forceinline__ float dot2f(uint32_t a, uint32_t b, float c) {
#if __has_builtin(__builtin_amdgcn_fdot2)
  H2U ua; ua.u = a; H2U ub; ub.u = b;
  return __builtin_amdgcn_fdot2(ua.h, ub.h, c, false);
#else
  H2U ua; ua.u = a; H2U ub; ub.u = b;
  return c + (float)ua.h.x*(float)ub.h.x + (float)ua.h.y*(float)ub.h.y;
#endif
}

__device__ __forceinline__ uint32_t packf2(float a, float b) {
  H2U u; u.h.x = (_Float16)a; u.h.y = (_Float16)b; return u.u;
}

__device__ __forceinline__ float sigm(float x) { return 1.0f / (1.0f + expf(-x)); }

// ---- pack W_ih (f32 [1200][300]) into f16x2 [150][1200]; W_hh into [152][1200] (rows 150,151 zero) ----
__global__ __launch_bounds__(256) void prep_w(
    const float* __restrict__ Wihf, const float* __restrict__ Wihb,
    const float* __restrict__ Whhf, const float* __restrict__ Whhb,
    uint32_t* __restrict__ wtih, uint32_t* __restrict__ wthh) {
  int i = blockIdx.x * 256 + threadIdx.x;
  int m = blockIdx.y;  // 0:ih_f 1:ih_b 2:hh_f 3:hh_b
  int kk, g;
  if (m < 2) {
    if (i >= KKP * G4) return;
    kk = i / G4; g = i % G4;
    const float* src = (m == 0) ? Wihf : Wihb;
    float2 v = *(const float2*)(src + (size_t)g * 300 + 2 * kk);
    wtih[(size_t)m * (KKP * G4) + i] = packf2(v.x, v.y);
  } else {
    if (i >= KKP2 * G4) return;
    kk = i / G4; g = i % G4;
    uint32_t u = 0u;
    if (kk < KKP) {
      const float* src = (m == 2) ? Whhf : Whhb;
      float2 v = *(const float2*)(src + (size_t)g * 300 + 2 * kk);
      u = packf2(v.x, v.y);
    }
    wthh[(size_t)(m - 2) * (KKP2 * G4) + i] = u;
  }
}

__global__ __launch_bounds__(256) void prep_bias(
    const float* __restrict__ bihf, const float* __restrict__ bhhf,
    const float* __restrict__ bihb, const float* __restrict__ bhhb,
    float* __restrict__ bias) {
  int i = blockIdx.x * 256 + threadIdx.x;
  if (i < G4) {
    bias[i]       = bihf[i] + bhhf[i];
    bias[G4 + i]  = bihb[i] + bhhb[i];
  }
}

// ---- gather embeddings -> packed f16x2, layout Ae[kk][m] (m = t*64+b) ----
__global__ __launch_bounds__(256) void gather_emb(
    const int* __restrict__ x, const float* __restrict__ emb,
    uint32_t* __restrict__ Ae) {
  __shared__ __align__(16) uint32_t buf[64 * KKP];
  __shared__ int idxs[64];
  int tid = threadIdx.x;
  int m0 = blockIdx.x * 64;
  if (tid < 64) {
    int mm = m0 + tid;
    idxs[tid] = x[(size_t)(mm & 63) * TSEQ + (mm >> 6)];   // x[b][t]
  }
  __syncthreads();
  for (int i = tid; i < 64 * KKP; i += 256) {
    int mm = i / KKP, kk = i % KKP;
    float2 v = *(const float2*)(emb + (size_t)idxs[mm] * EMB + 2 * kk);
    buf[i] = packf2(v.x, v.y);
  }
  __syncthreads();
  for (int i = tid; i < 64 * KKP; i += 256) {
    int kk = i >> 6, mm = i & 63;
    Ae[(size_t)kk * MTOT + m0 + mm] = buf[mm * KKP + kk];
  }
}

// ---- pre = emb @ W_ih^T + (b_ih+b_hh), stored f16 [2][32768][1200] ----
__global__ __launch_bounds__(256) void embed_pre(
    const uint32_t* __restrict__ Ae, const uint32_t* __restrict__ wtih,
    const float* __restrict__ bias, _Float16* __restrict__ pre) {
  int d = blockIdx.z;
  int m0 = blockIdx.x * 64, n0 = blockIdx.y * 64;
  int tid = threadIdx.x;
  __shared__ __align__(16) uint32_t As[30 * 64];
  __shared__ __align__(16) uint32_t Bs[30 * 64];
  const uint32_t* W = wtih + (size_t)d * (KKP * G4);
  int tx = tid & 15, ty = tid >> 4;
  float acc[4][4] = {};
  for (int c = 0; c < 5; ++c) {
    int kb = c * 30;
    for (int i = tid; i < 30 * 64; i += 256) {
      int kk = i >> 6, mm = i & 63;
      As[i] = Ae[(size_t)(kb + kk) * MTOT + m0 + mm];
    }
    for (int i = tid; i < 30 * 64; i += 256) {
      int kk = i >> 6, cc = i & 63;
      int g = n0 + cc;
      Bs[i] = (g < G4) ? W[(size_t)(kb + kk) * G4 + g] : 0u;
    }
    __syncthreads();
    #pragma unroll 5
    for (int kk = 0; kk < 30; ++kk) {
      uint4 a4 = *(const uint4*)&As[kk * 64 + ty * 4];
      uint4 b4 = *(const uint4*)&Bs[kk * 64 + tx * 4];
      uint32_t av[4] = {a4.x, a4.y, a4.z, a4.w};
      uint32_t bv[4] = {b4.x, b4.y, b4.z, b4.w};
      #pragma unroll
      for (int im = 0; im < 4; ++im)
        #pragma unroll
        for (int in = 0; in < 4; ++in)
          acc[im][in] = dot2f(av[im], bv[in], acc[im][in]);
    }
    __syncthreads();
  }
  #pragma unroll
  for (int im = 0; im < 4; ++im) {
    int mm = m0 + ty * 4 + im;
    #pragma unroll
    for (int in = 0; in < 4; ++in) {
      int g = n0 + tx * 4 + in;
      if (g < G4)
        pre[((size_t)d * MTOT + mm) * G4 + g] = (_Float16)(acc[im][in] + bias[d * G4 + g]);
    }
  }
}

// ---- the sequential LSTM: one 1024-thread workgroup per (dir, batch) chain ----
// W_hh streamed from L2 each step (720 KB, resident); 16 waves/CU for latency hiding.
__global__ __launch_bounds__(1024) void lstm(
    const uint32_t* __restrict__ wthh, const _Float16* __restrict__ pre,
    float* __restrict__ hs) {
  int d = blockIdx.x >> 6;
  int b = blockIdx.x & 63;
  int tid = threadIdx.x;
  __shared__ __align__(16) uint32_t h2s[KKP2];
  __shared__ float cs[HID];
  __shared__ float gate[G4];
  for (int i = tid; i < KKP2; i += 1024) h2s[i] = 0u;
  for (int i = tid; i < HID; i += 1024) cs[i] = 0.0f;
  __syncthreads();
  const uint32_t* Wd = wthh + (size_t)d * (KKP2 * G4);
  const bool has2 = tid < (G4 - 1024);   // tid < 176
  for (int s = 0; s < TSEQ; ++s) {
    int t = d ? (TSEQ - 1 - s) : s;
    const _Float16* prow = pre + ((size_t)d * MTOT + (size_t)t * NB + b) * G4;
    float acc0 = 0.f, acc1 = 0.f;
    #pragma unroll 2
    for (int kk = 0; kk < KKP2; kk += 4) {
      uint4 h4 = *(const uint4*)&h2s[kk];
      const uint32_t* wr = Wd + (size_t)kk * G4 + tid;
      uint32_t w00 = wr[0],       w01 = wr[G4],       w02 = wr[2*G4],       w03 = wr[3*G4];
      if (has2) {
        uint32_t w10 = wr[1024], w11 = wr[G4+1024], w12 = wr[2*G4+1024], w13 = wr[3*G4+1024];
        acc1 = dot2f(w10, h4.x, acc1);
        acc1 = dot2f(w11, h4.y, acc1);
        acc1 = dot2f(w12, h4.z, acc1);
        acc1 = dot2f(w13, h4.w, acc1);
      }
      acc0 = dot2f(w00, h4.x, acc0);
      acc0 = dot2f(w01, h4.y, acc0);
      acc0 = dot2f(w02, h4.z, acc0);
      acc0 = dot2f(w03, h4.w, acc0);
    }
    gate[tid] = acc0 + (float)prow[tid];
    if (has2) gate[tid + 1024] = acc1 + (float)prow[tid + 1024];
    __syncthreads();
    if (tid < HID) {
      float iv = sigm(gate[tid]);
      float fv = sigm(gate[HID + tid]);
      float gv = tanhf(gate[2*HID + tid]);
      float ov = sigm(gate[3*HID + tid]);
      float c = fv * cs[tid] + iv * gv;
      cs[tid] = c;
      float h = ov * tanhf(c);
      ((_Float16*)h2s)[tid] = (_Float16)h;
      hs[((size_t)d * MTOT + (size_t)t * NB + b) * HID + tid] = h;
    }
    __syncthreads();
  }
}

// ---- logits = [h_f,h_b] @ W_lin^T + b_lin ; probs = softmax ----
__global__ __launch_bounds__(256) void logits_probs(
    const float* __restrict__ hs, const float* __restrict__ Wlin,
    const float* __restrict__ blin, float* __restrict__ probs) {
  __shared__ float Ws[NT * 600];
  __shared__ float bs[NT];
  int tid = threadIdx.x;
  for (int i = tid; i < NT * 600; i += 256) Ws[i] = Wlin[i];
  if (tid < NT) bs[tid] = blin[tid];
  __syncthreads();
  int wave = tid >> 6, lane = tid & 63;
  int tb = blockIdx.x * 4 + wave;     // = t*64 + b
  const float* hf = hs + (size_t)tb * HID;
  const float* hb = hs + ((size_t)MTOT + tb) * HID;
  float p[NT];
  #pragma unroll
  for (int k = 0; k < NT; ++k) p[k] = 0.f;
  for (int e = lane; e < HID; e += 64) {
    float vf = hf[e], vb = hb[e];
    #pragma unroll
    for (int k = 0; k < NT; ++k)
      p[k] += vf * Ws[k * 600 + e] + vb * Ws[k * 600 + 300 + e];
  }
  #pragma unroll
  for (int off = 32; off > 0; off >>= 1)
    #pragma unroll
    for (int k = 0; k < NT; ++k) p[k] += __shfl_xor(p[k], off);
  float l[NT]; float mx = -1e30f;
  #pragma unroll
  for (int k = 0; k < NT; ++k) { l[k] = p[k] + bs[k]; mx = fmaxf(mx, l[k]); }
  float ssum = 0.f;
  #pragma unroll
  for (int k = 0; k < NT; ++k) ssum = ssum + expf(l[k] - mx);
  int t = tb >> 6, b = tb & 63;
  if (lane < NT)
    probs[((size_t)b * TSEQ + t) * NT + lane] = expf(l[lane] - mx) / ssum;
}

// ---- CRF numerator per batch ----
__global__ __launch_bounds__(256) void crf_num(
    const int* __restrict__ y, const float* __restrict__ probs,
    const float* __restrict__ strt, const float* __restrict__ endt,
    const float* __restrict__ trans, float* __restrict__ nums) {
  int b = blockIdx.x, tid = threadIdx.x;
  __shared__ float r1[256], r2[256];
  float s = 0.f, cnt = 0.f;
  for (int t = tid; t < TSEQ; t += 256) {
    int yc = y[(size_t)b * TSEQ + t];
    cnt += (yc != -1) ? 1.f : 0.f;
    if (t >= 1) {
      int yp = y[(size_t)b * TSEQ + t - 1];
      float mask = (yc != -1) ? 1.f : 0.f;
      s += mask * (trans[yp * NT + yc] + probs[((size_t)b * TSEQ + t) * NT + yc]);
    }
  }
  r1[tid] = s; r2[tid] = cnt;
  __syncthreads();
  for (int off = 128; off > 0; off >>= 1) {
    if (tid < off) { r1[tid] += r1[tid + off]; r2[tid] += r2[tid + off]; }
    __syncthreads();
  }
  if (tid == 0) {
    int y0 = y[(size_t)b * TSEQ];
    int seqlen = (int)(r2[0] + 0.5f);
    int ylast = y[(size_t)b * TSEQ + seqlen - 1];
    nums[b] = strt[y0] + probs[((size_t)b * TSEQ) * NT + y0] + r1[0] + endt[ylast];
  }
}

// ---- CRF forward algorithm (denominator) per batch ----
__global__ __launch_bounds__(64) void crf_alpha(
    const int* __restrict__ y, const float* __restrict__ probs,
    const float* __restrict__ strt, const float* __restrict__ endt,
    const float* __restrict__ trans, float* __restrict__ dens) {
  int b = blockIdx.x, lane = threadIdx.x;
  __shared__ float tr[NT * NT];
  __shared__ float al[NT];
  if (lane < NT * NT) tr[lane] = trans[lane];
  if (lane < NT) al[lane] = strt[lane] + probs[((size_t)b * TSEQ) * NT + lane];
  __syncthreads();
  for (int t = 1; t < TSEQ; ++t) {
    float nxt = 0.f;
    int m = (y[(size_t)b * TSEQ + t] != -1);
    if (lane < NT) {
      float e = probs[((size_t)b * TSEQ + t) * NT + lane];
      float mx = -1e30f;
      #pragma unroll
      for (int j = 0; j < NT; ++j) mx = fmaxf(mx, al[j] + tr[j * NT + lane]);
      float sum = 0.f;
      #pragma unroll
      for (int j = 0; j < NT; ++j) sum += expf(al[j] + tr[j * NT + lane] - mx);
      nxt = e + mx + logf(sum);
    }
    __syncthreads();
    if (lane < NT && m) al[lane] = nxt;
    __syncthreads();
  }
  if (lane == 0) {
    float mx = -1e30f;
    for (int k = 0; k < NT; ++k) mx = fmaxf(mx, al[k] + endt[k]);
    float sum = 0.f;
    for (int k = 0; k < NT; ++k) sum += expf(al[k] + endt[k] - mx);
    dens[b] = mx + logf(sum);
  }
}

__global__ __launch_bounds__(64) void final_sum(
    const float* __restrict__ nums, const float* __restrict__ dens,
    float* __restrict__ out) {
  __shared__ float r[64];
  int tid = threadIdx.x;
  r[tid] = nums[tid] - dens[tid];
  __syncthreads();
  for (int off = 32; off > 0; off >>= 1) {
    if (tid < off) r[tid] += r[tid + off];
    __syncthreads();
  }
  if (tid == 0) out[(size_t)MTOT * NT] = -r[0];
}

extern "C" void kernel_launch(void* const* d_in, const int* in_sizes, int n_in,
                              void* d_out, int out_size, void* d_ws, size_t ws_size,
                              hipStream_t stream) {
  (void)in_sizes; (void)n_in; (void)out_size;
  const int*   x     = (const int*)d_in[0];
  const int*   y     = (const int*)d_in[1];
  const float* emb   = (const float*)d_in[2];
  const float* Wihf  = (const float*)d_in[3];
  const float* Whhf  = (const float*)d_in[4];
  const float* bihf  = (const float*)d_in[5];
  const float* bhhf  = (const float*)d_in[6];
  const float* Wihb  = (const float*)d_in[7];
  const float* Whhb  = (const float*)d_in[8];
  const float* bihb  = (const float*)d_in[9];
  const float* bhhb  = (const float*)d_in[10];
  const float* Wlin  = (const float*)d_in[11];
  const float* blin  = (const float*)d_in[12];
  const float* strt  = (const float*)d_in[13];
  const float* endt  = (const float*)d_in[14];
  const float* trans = (const float*)d_in[15];
  float* outp = (float*)d_out;

  char* ws = (char*)d_ws;
  const size_t OFF_WTIH = 0;                   // 2*150*1200*4 = 1,440,000 B
  const size_t OFF_WTHH = 1440000;             // 2*152*1200*4 = 1,459,200 B
  const size_t OFF_BIAS = 2899200;             // 9,600 B
  const size_t OFF_NUMS = 2908800;             // 256 B
  const size_t OFF_DENS = 2909056;             // 256 B
  const size_t OFF_AE   = 2909440;             // 19,660,800 B
  const size_t OFF_HS   = 22570240;            // 78,643,200 B
  const size_t OFF_PRE  = 101213440;           // 157,286,400 B -> end 258,499,840
  if (ws_size < 258499840ull) return;

  uint32_t* wtih = (uint32_t*)(ws + OFF_WTIH);
  uint32_t* wthh = (uint32_t*)(ws + OFF_WTHH);
  float*    bias = (float*)(ws + OFF_BIAS);
  float*    nums = (float*)(ws + OFF_NUMS);
  float*    dens = (float*)(ws + OFF_DENS);
  uint32_t* Ae   = (uint32_t*)(ws + OFF_AE);
  float*    hsb  = (float*)(ws + OFF_HS);
  _Float16* pre  = (_Float16*)(ws + OFF_PRE);

  prep_w<<<dim3((KKP2 * G4 + 255) / 256, 4), 256, 0, stream>>>(Wihf, Wihb, Whhf, Whhb, wtih, wthh);
  prep_bias<<<dim3((G4 + 255) / 256), 256, 0, stream>>>(bihf, bhhf, bihb, bhhb, bias);
  gather_emb<<<dim3(MTOT / 64), 256, 0, stream>>>(x, emb, Ae);
  embed_pre<<<dim3(MTOT / 64, (G4 + 63) / 64, 2), 256, 0, stream>>>(Ae, wtih, bias, pre);
  lstm<<<dim3(128), 1024, 0, stream>>>(wthh, pre, hsb);
  logits_probs<<<dim3(MTOT / 4), 256, 0, stream>>>(hsb, Wlin, blin, outp);
  crf_num<<<dim3(NB), 256, 0, stream>>>(y, outp, strt, endt, trans, nums);
  crf_alpha<<<dim3(NB), 64, 0, stream>>>(y, outp, strt, endt, trans, dens);
  final_sum<<<1, 64, 0, stream>>>(nums, dens, outp);
}

// Round 3
// 5595.987 us; speedup vs baseline: 2.3834x; 1.0593x over previous
//
#include <hip/hip_runtime.h>
#include <stdint.h>

#define TSEQ 512
#define NB   64
#define EMB  300
#define HID  300
#define G4   1200
#define KKP  150     // pairs of K (300/2)
#define NT   9
#define MTOT (TSEQ*NB)   // 32768

// MFMA lstm geometry
#define NP 19          // hid blocks of 16 (covers 304, last block padded)
#define NQ 4           // batch groups of 16
#define NWG (2*NQ*NP)  // 152 workgroups
#define KSTEPS 10      // K padded to 320 = 10 * 32

typedef _Float16 h2v __attribute__((ext_vector_type(2)));
typedef _Float16 f16x8 __attribute__((ext_vector_type(8)));
typedef float f32x4 __attribute__((ext_vector_type(4)));
union H2U { uint32_t u; h2v h; };

__device__ __forceinline__ float dot2f(uint32_t a, uint32_t b, float c) {
#if __has_builtin(__builtin_amdgcn_fdot2)
  H2U ua; ua.u = a; H2U ub; ub.u = b;
  return __builtin_amdgcn_fdot2(ua.h, ub.h, c, false);
#else
  H2U ua; ua.u = a; H2U ub; ub.u = b;
  return c + (float)ua.h.x*(float)ub.h.x + (float)ua.h.y*(float)ub.h.y;
#endif
}

__device__ __forceinline__ uint32_t packf2(float a, float b) {
  H2U u; u.h.x = (_Float16)a; u.h.y = (_Float16)b; return u.u;
}

__device__ __forceinline__ float sigm(float x) { return 1.0f / (1.0f + expf(-x)); }

// ---- pack W_ih (f32 [1200][300]) into f16x2 [150][1200] for embed_pre ----
__global__ __launch_bounds__(256) void prep_wih(
    const float* __restrict__ Wihf, const float* __restrict__ Wihb,
    uint32_t* __restrict__ wtih) {
  int i = blockIdx.x * 256 + threadIdx.x;
  if (i >= KKP * G4) return;
  int m = blockIdx.y;  // 0:ih_f 1:ih_b
  int kk = i / G4, g = i % G4;
  const float* src = (m == 0) ? Wihf : Wihb;
  float2 v = *(const float2*)(src + (size_t)g * 300 + 2 * kk);
  wtih[(size_t)m * (KKP * G4) + i] = packf2(v.x, v.y);
}

__global__ __launch_bounds__(256) void prep_bias(
    const float* __restrict__ bihf, const float* __restrict__ bhhf,
    const float* __restrict__ bihb, const float* __restrict__ bhhb,
    float* __restrict__ bias) {
  int i = blockIdx.x * 256 + threadIdx.x;
  if (i < G4) {
    bias[i]       = bihf[i] + bhhf[i];
    bias[G4 + i]  = bihb[i] + bhhb[i];
  }
}

// ---- pack W_hh into per-lane MFMA A-fragments ----
// blk = ((d*NP + p)*4 + gamma)*KSTEPS + ks ; 64 threads = lanes.
// A-frag layout (16x16x32 f16): lane l holds A[row = l&15][k = (l>>4)*8 + e], e=0..7,
// packed as 4 dwords of f16-pairs (k even, k odd).
__global__ __launch_bounds__(64) void prep_w2(
    const float* __restrict__ Whhf, const float* __restrict__ Whhb,
    uint32_t* __restrict__ w2) {
  int blk = blockIdx.x;
  int ks = blk % KSTEPS; int tmp = blk / KSTEPS;
  int gamma = tmp & 3; tmp >>= 2;
  int p = tmp % NP; int d = tmp / NP;
  int lane = threadIdx.x;
  const float* W = d ? Whhb : Whhf;
  int hid = 16 * p + (lane & 15);
  int k0 = ks * 32 + (lane >> 4) * 8;
  float vals[8];
  #pragma unroll
  for (int e = 0; e < 8; ++e) {
    int k = k0 + e;
    vals[e] = (hid < 300 && k < 300) ? W[(size_t)(gamma * 300 + hid) * 300 + k] : 0.0f;
  }
  uint4 dw;
  dw.x = packf2(vals[0], vals[1]);
  dw.y = packf2(vals[2], vals[3]);
  dw.z = packf2(vals[4], vals[5]);
  dw.w = packf2(vals[6], vals[7]);
  *(uint4*)(w2 + ((size_t)blk * 64 + lane) * 4) = dw;
}

// ---- zero sync flags + h2 double buffer (must run every launch) ----
__global__ __launch_bounds__(256) void init_sync(
    uint32_t* __restrict__ flags, uint32_t* __restrict__ h2g) {
  int i = blockIdx.x * 256 + threadIdx.x;
  if (i < 256) flags[i] = 0;
  if (i < 2 * 2 * 160 * 64) h2g[i] = 0;
}

// ---- gather embeddings -> packed f16x2, layout Ae[kk][m] (m = t*64+b) ----
__global__ __launch_bounds__(256) void gather_emb(
    const int* __restrict__ x, const float* __restrict__ emb,
    uint32_t* __restrict__ Ae) {
  __shared__ __align__(16) uint32_t buf[64 * KKP];
  __shared__ int idxs[64];
  int tid = threadIdx.x;
  int m0 = blockIdx.x * 64;
  if (tid < 64) {
    int mm = m0 + tid;
    idxs[tid] = x[(size_t)(mm & 63) * TSEQ + (mm >> 6)];   // x[b][t]
  }
  __syncthreads();
  for (int i = tid; i < 64 * KKP; i += 256) {
    int mm = i / KKP, kk = i % KKP;
    float2 v = *(const float2*)(emb + (size_t)idxs[mm] * EMB + 2 * kk);
    buf[i] = packf2(v.x, v.y);
  }
  __syncthreads();
  for (int i = tid; i < 64 * KKP; i += 256) {
    int kk = i >> 6, mm = i & 63;
    Ae[(size_t)kk * MTOT + m0 + mm] = buf[mm * KKP + kk];
  }
}

// ---- pre = emb @ W_ih^T + (b_ih+b_hh), stored f16 [2][32768][1200] ----
__global__ __launch_bounds__(256) void embed_pre(
    const uint32_t* __restrict__ Ae, const uint32_t* __restrict__ wtih,
    const float* __restrict__ bias, _Float16* __restrict__ pre) {
  int d = blockIdx.z;
  int m0 = blockIdx.x * 64, n0 = blockIdx.y * 64;
  int tid = threadIdx.x;
  __shared__ __align__(16) uint32_t As[30 * 64];
  __shared__ __align__(16) uint32_t Bs[30 * 64];
  const uint32_t* W = wtih + (size_t)d * (KKP * G4);
  int tx = tid & 15, ty = tid >> 4;
  float acc[4][4] = {};
  for (int c = 0; c < 5; ++c) {
    int kb = c * 30;
    for (int i = tid; i < 30 * 64; i += 256) {
      int kk = i >> 6, mm = i & 63;
      As[i] = Ae[(size_t)(kb + kk) * MTOT + m0 + mm];
    }
    for (int i = tid; i < 30 * 64; i += 256) {
      int kk = i >> 6, cc = i & 63;
      int g = n0 + cc;
      Bs[i] = (g < G4) ? W[(size_t)(kb + kk) * G4 + g] : 0u;
    }
    __syncthreads();
    #pragma unroll 5
    for (int kk = 0; kk < 30; ++kk) {
      uint4 a4 = *(const uint4*)&As[kk * 64 + ty * 4];
      uint4 b4 = *(const uint4*)&Bs[kk * 64 + tx * 4];
      uint32_t av[4] = {a4.x, a4.y, a4.z, a4.w};
      uint32_t bv[4] = {b4.x, b4.y, b4.z, b4.w};
      #pragma unroll
      for (int im = 0; im < 4; ++im)
        #pragma unroll
        for (int in = 0; in < 4; ++in)
          acc[im][in] = dot2f(av[im], bv[in], acc[im][in]);
    }
    __syncthreads();
  }
  #pragma unroll
  for (int im = 0; im < 4; ++im) {
    int mm = m0 + ty * 4 + im;
    #pragma unroll
    for (int in = 0; in < 4; ++in) {
      int g = n0 + tx * 4 + in;
      if (g < G4)
        pre[((size_t)d * MTOT + mm) * G4 + g] = (_Float16)(acc[im][in] + bias[d * G4 + g]);
    }
  }
}

// ---- MFMA LSTM: WG = (dir d, batch-group q of 16, hid-block p of 16) ----
// Wave gamma computes gate gamma's 16x16 tile; weights live in registers.
// h published cross-WG via agent-scope atomics (MALL), parity double buffer,
// per-WG monotonic flags; only the 19 WGs of (d,q) synchronize.
__global__ __launch_bounds__(256) void lstm_mfma(
    const uint32_t* __restrict__ w2, const _Float16* __restrict__ pre,
    uint32_t* __restrict__ h2g, uint32_t* __restrict__ flags,
    float* __restrict__ hs) {
  const int wg = blockIdx.x;           // ((d*NQ+q)*NP + p)
  const int p  = wg % NP;
  const int dq = wg / NP;
  const int q  = dq % NQ;
  const int d  = dq / NQ;
  const int tid = threadIdx.x;
  const int gamma = tid >> 6;          // wave = gate
  const int lane  = tid & 63;

  __shared__ uint32_t h2L[160 * 16];   // [kk][batch-local] f16-pairs
  __shared__ float gateL[4 * 16 * 16]; // [gate][hid-local][batch-local]

  for (int i = tid; i < 160 * 16; i += 256) h2L[i] = 0u;  // rows >=150 stay 0

  // preload A fragments (weights) into registers: 10 ksteps x uint4
  uint4 afr[KSTEPS];
  const int blk0 = ((d * NP + p) * 4 + gamma) * KSTEPS;
  #pragma unroll
  for (int ks = 0; ks < KSTEPS; ++ks)
    afr[ks] = *(const uint4*)(w2 + (size_t)(blk0 + ks) * 256 + lane * 4);

  // cell-update mapping: thread -> (hid-local, batch-local)
  const int hidl = tid >> 4;
  const int bl = tid & 15;
  const int hid = 16 * p + hidl;
  const int bglob = 16 * q + bl;
  float cstate = 0.0f;

  // acc/pre mapping: lane covers rows rowh0..rowh0+3, col = batch (lane&15)
  const int rowh0 = 16 * p + ((lane >> 4) * 4);
  const bool rowok = rowh0 < 300;
  const int bpre = 16 * q + (lane & 15);

  const uint32_t* fl = flags + (d * NQ + q) * NP;  // group's 19 flags
  uint32_t* myflag = flags + wg;

  __syncthreads();

  for (int s = 0; s < TSEQ; ++s) {
    const int t = d ? (TSEQ - 1 - s) : s;

    // prefetch pre slice (independent of h) before the poll
    uint2 pr = make_uint2(0u, 0u);
    if (rowok)
      pr = *(const uint2*)(pre + ((size_t)d * MTOT + (size_t)t * NB + bpre) * G4
                           + (gamma * 300 + rowh0));

    // wait: all group members published step s-1 (flag >= s)
    if (s > 0 && tid < 64) {
      bool done = false;
      while (!done) {
        uint32_t v = 0xFFFFFFFFu;
        if (lane < NP)
          v = __hip_atomic_load(fl + lane, __ATOMIC_ACQUIRE, __HIP_MEMORY_SCOPE_AGENT);
        done = __all((int)(v >= (uint32_t)s));
      }
    }
    __syncthreads();

    // load h(s-1) from parity buffer into LDS (kk 0..149 x 16 batches)
    const uint32_t* src = h2g + (size_t)(((s + 1) & 1) * 2 + d) * 160 * 64;
    for (int i = tid; i < KKP * 16; i += 256) {
      int kk = i >> 4, b = i & 15;
      uint32_t v = __hip_atomic_load(src + kk * 64 + 16 * q + b,
                                     __ATOMIC_RELAXED, __HIP_MEMORY_SCOPE_AGENT);
      h2L[kk * 16 + b] = v;
    }
    __syncthreads();

    // acc = pre (bias already folded in), then 10 MFMAs over K=320
    f32x4 acc;
    {
      union { uint2 u; _Float16 h[4]; } cv; cv.u = pr;
      acc[0] = (float)cv.h[0]; acc[1] = (float)cv.h[1];
      acc[2] = (float)cv.h[2]; acc[3] = (float)cv.h[3];
    }
    #pragma unroll
    for (int ks = 0; ks < KSTEPS; ++ks) {
      union { uint32_t u[4]; f16x8 v; } bu;
      int base = (ks * 16 + (lane >> 4) * 4) * 16 + (lane & 15);
      bu.u[0] = h2L[base];
      bu.u[1] = h2L[base + 16];
      bu.u[2] = h2L[base + 32];
      bu.u[3] = h2L[base + 48];
      union { uint4 u; f16x8 v; } au; au.u = afr[ks];
      acc = __builtin_amdgcn_mfma_f32_16x16x32_f16(au.v, bu.v, acc, 0, 0, 0);
    }

    // exchange gates through LDS: D layout row=(lane>>4)*4+r, col=lane&15
    {
      int rbase = (lane >> 4) * 4, col = lane & 15;
      #pragma unroll
      for (int r = 0; r < 4; ++r)
        gateL[(gamma * 16 + rbase + r) * 16 + col] = acc[r];
    }
    __syncthreads();

    // cell update (c stays in this thread's register for all 512 steps)
    float gi = gateL[(0 * 16 + hidl) * 16 + bl];
    float gf = gateL[(1 * 16 + hidl) * 16 + bl];
    float gg = gateL[(2 * 16 + hidl) * 16 + bl];
    float go = gateL[(3 * 16 + hidl) * 16 + bl];
    float iv = sigm(gi), fv = sigm(gf), gv = tanhf(gg), ov = sigm(go);
    cstate = fv * cstate + iv * gv;
    float h = ov * tanhf(cstate);

    if (hid < 300)
      hs[((size_t)d * MTOT + (size_t)t * NB + bglob) * HID + hid] = h;

    // publish packed h pair (hid even thread packs with hid+1 via shfl)
    float hpart = __shfl_xor(h, 16);
    if ((hidl & 1) == 0 && hid < 300) {
      uint32_t dw = packf2(h, hpart);
      int kk = 8 * p + (hidl >> 1);
      uint32_t* dst = h2g + ((size_t)((s & 1) * 2 + d) * 160 + kk) * 64 + bglob;
      __hip_atomic_store(dst, dw, __ATOMIC_RELAXED, __HIP_MEMORY_SCOPE_AGENT);
    }
    __syncthreads();   // drains vmcnt for all waves before flag release
    if (tid == 0)
      __hip_atomic_store(myflag, (uint32_t)(s + 1), __ATOMIC_RELEASE,
                         __HIP_MEMORY_SCOPE_AGENT);
  }
}

// ---- logits = [h_f,h_b] @ W_lin^T + b_lin ; probs = softmax ----
__global__ __launch_bounds__(256) void logits_probs(
    const float* __restrict__ hs, const float* __restrict__ Wlin,
    const float* __restrict__ blin, float* __restrict__ probs) {
  __shared__ float Ws[NT * 600];
  __shared__ float bs[NT];
  int tid = threadIdx.x;
  for (int i = tid; i < NT * 600; i += 256) Ws[i] = Wlin[i];
  if (tid < NT) bs[tid] = blin[tid];
  __syncthreads();
  int wave = tid >> 6, lane = tid & 63;
  int tb = blockIdx.x * 4 + wave;     // = t*64 + b
  const float* hf = hs + (size_t)tb * HID;
  const float* hb = hs + ((size_t)MTOT + tb) * HID;
  float p[NT];
  #pragma unroll
  for (int k = 0; k < NT; ++k) p[k] = 0.f;
  for (int e = lane; e < HID; e += 64) {
    float vf = hf[e], vb = hb[e];
    #pragma unroll
    for (int k = 0; k < NT; ++k)
      p[k] += vf * Ws[k * 600 + e] + vb * Ws[k * 600 + 300 + e];
  }
  #pragma unroll
  for (int off = 32; off > 0; off >>= 1)
    #pragma unroll
    for (int k = 0; k < NT; ++k) p[k] += __shfl_xor(p[k], off);
  float l[NT]; float mx = -1e30f;
  #pragma unroll
  for (int k = 0; k < NT; ++k) { l[k] = p[k] + bs[k]; mx = fmaxf(mx, l[k]); }
  float ssum = 0.f;
  #pragma unroll
  for (int k = 0; k < NT; ++k) ssum = ssum + expf(l[k] - mx);
  int t = tb >> 6, b = tb & 63;
  if (lane < NT)
    probs[((size_t)b * TSEQ + t) * NT + lane] = expf(l[lane] - mx) / ssum;
}

// ---- CRF numerator per batch ----
__global__ __launch_bounds__(256) void crf_num(
    const int* __restrict__ y, const float* __restrict__ probs,
    const float* __restrict__ strt, const float* __restrict__ endt,
    const float* __restrict__ trans, float* __restrict__ nums) {
  int b = blockIdx.x, tid = threadIdx.x;
  __shared__ float r1[256], r2[256];
  float s = 0.f, cnt = 0.f;
  for (int t = tid; t < TSEQ; t += 256) {
    int yc = y[(size_t)b * TSEQ + t];
    cnt += (yc != -1) ? 1.f : 0.f;
    if (t >= 1) {
      int yp = y[(size_t)b * TSEQ + t - 1];
      float mask = (yc != -1) ? 1.f : 0.f;
      s += mask * (trans[yp * NT + yc] + probs[((size_t)b * TSEQ + t) * NT + yc]);
    }
  }
  r1[tid] = s; r2[tid] = cnt;
  __syncthreads();
  for (int off = 128; off > 0; off >>= 1) {
    if (tid < off) { r1[tid] += r1[tid + off]; r2[tid] += r2[tid + off]; }
    __syncthreads();
  }
  if (tid == 0) {
    int y0 = y[(size_t)b * TSEQ];
    int seqlen = (int)(r2[0] + 0.5f);
    int ylast = y[(size_t)b * TSEQ + seqlen - 1];
    nums[b] = strt[y0] + probs[((size_t)b * TSEQ) * NT + y0] + r1[0] + endt[ylast];
  }
}

// ---- CRF forward algorithm (denominator) per batch ----
__global__ __launch_bounds__(64) void crf_alpha(
    const int* __restrict__ y, const float* __restrict__ probs,
    const float* __restrict__ strt, const float* __restrict__ endt,
    const float* __restrict__ trans, float* __restrict__ dens) {
  int b = blockIdx.x, lane = threadIdx.x;
  __shared__ float tr[NT * NT];
  __shared__ float al[NT];
  if (lane < NT * NT) tr[lane] = trans[lane];
  if (lane < NT) al[lane] = strt[lane] + probs[((size_t)b * TSEQ) * NT + lane];
  __syncthreads();
  for (int t = 1; t < TSEQ; ++t) {
    float nxt = 0.f;
    int m = (y[(size_t)b * TSEQ + t] != -1);
    if (lane < NT) {
      float e = probs[((size_t)b * TSEQ + t) * NT + lane];
      float mx = -1e30f;
      #pragma unroll
      for (int j = 0; j < NT; ++j) mx = fmaxf(mx, al[j] + tr[j * NT + lane]);
      float sum = 0.f;
      #pragma unroll
      for (int j = 0; j < NT; ++j) sum += expf(al[j] + tr[j * NT + lane] - mx);
      nxt = e + mx + logf(sum);
    }
    __syncthreads();
    if (lane < NT && m) al[lane] = nxt;
    __syncthreads();
  }
  if (lane == 0) {
    float mx = -1e30f;
    for (int k = 0; k < NT; ++k) mx = fmaxf(mx, al[k] + endt[k]);
    float sum = 0.f;
    for (int k = 0; k < NT; ++k) sum += expf(al[k] + endt[k] - mx);
    dens[b] = mx + logf(sum);
  }
}

__global__ __launch_bounds__(64) void final_sum(
    const float* __restrict__ nums, const float* __restrict__ dens,
    float* __restrict__ out) {
  __shared__ float r[64];
  int tid = threadIdx.x;
  r[tid] = nums[tid] - dens[tid];
  __syncthreads();
  for (int off = 32; off > 0; off >>= 1) {
    if (tid < off) r[tid] += r[tid + off];
    __syncthreads();
  }
  if (tid == 0) out[(size_t)MTOT * NT] = -r[0];
}

extern "C" void kernel_launch(void* const* d_in, const int* in_sizes, int n_in,
                              void* d_out, int out_size, void* d_ws, size_t ws_size,
                              hipStream_t stream) {
  (void)in_sizes; (void)n_in; (void)out_size;
  const int*   x     = (const int*)d_in[0];
  const int*   y     = (const int*)d_in[1];
  const float* emb   = (const float*)d_in[2];
  const float* Wihf  = (const float*)d_in[3];
  const float* Whhf  = (const float*)d_in[4];
  const float* bihf  = (const float*)d_in[5];
  const float* bhhf  = (const float*)d_in[6];
  const float* Wihb  = (const float*)d_in[7];
  const float* Whhb  = (const float*)d_in[8];
  const float* bihb  = (const float*)d_in[9];
  const float* bhhb  = (const float*)d_in[10];
  const float* Wlin  = (const float*)d_in[11];
  const float* blin  = (const float*)d_in[12];
  const float* strt  = (const float*)d_in[13];
  const float* endt  = (const float*)d_in[14];
  const float* trans = (const float*)d_in[15];
  float* outp = (float*)d_out;

  char* ws = (char*)d_ws;
  const size_t OFF_WTIH  = 0;            // 1,440,000
  const size_t OFF_W2    = 1440000;      // 1,556,480
  const size_t OFF_BIAS  = 2996480;      // 9,600
  const size_t OFF_NUMS  = 3006080;      // 256
  const size_t OFF_DENS  = 3006336;      // 256
  const size_t OFF_FLAGS = 3006592;      // 1,024
  const size_t OFF_H2G   = 3007616;      // 163,840
  const size_t OFF_AE    = 3171456;      // 19,660,800
  const size_t OFF_HS    = 22832256;     // 78,643,200
  const size_t OFF_PRE   = 101475456;    // 157,286,400 -> end 258,761,856
  if (ws_size < 258761856ull) return;

  uint32_t* wtih  = (uint32_t*)(ws + OFF_WTIH);
  uint32_t* w2    = (uint32_t*)(ws + OFF_W2);
  float*    bias  = (float*)(ws + OFF_BIAS);
  float*    nums  = (float*)(ws + OFF_NUMS);
  float*    dens  = (float*)(ws + OFF_DENS);
  uint32_t* flags = (uint32_t*)(ws + OFF_FLAGS);
  uint32_t* h2g   = (uint32_t*)(ws + OFF_H2G);
  uint32_t* Ae    = (uint32_t*)(ws + OFF_AE);
  float*    hsb   = (float*)(ws + OFF_HS);
  _Float16* pre   = (_Float16*)(ws + OFF_PRE);

  prep_wih<<<dim3((KKP * G4 + 255) / 256, 2), 256, 0, stream>>>(Wihf, Wihb, wtih);
  prep_bias<<<dim3((G4 + 255) / 256), 256, 0, stream>>>(bihf, bhhf, bihb, bhhb, bias);
  prep_w2<<<dim3(2 * NP * 4 * KSTEPS), 64, 0, stream>>>(Whhf, Whhb, w2);
  init_sync<<<dim3(160), 256, 0, stream>>>(flags, h2g);
  gather_emb<<<dim3(MTOT / 64), 256, 0, stream>>>(x, emb, Ae);
  embed_pre<<<dim3(MTOT / 64, (G4 + 63) / 64, 2), 256, 0, stream>>>(Ae, wtih, bias, pre);
  lstm_mfma<<<dim3(NWG), 256, 0, stream>>>(w2, pre, h2g, flags, hsb);
  logits_probs<<<dim3(MTOT / 4), 256, 0, stream>>>(hsb, Wlin, blin, outp);
  crf_num<<<dim3(NB), 256, 0, stream>>>(y, outp, strt, endt, trans, nums);
  crf_alpha<<<dim3(NB), 64, 0, stream>>>(y, outp, strt, endt, trans, dens);
  final_sum<<<1, 64, 0, stream>>>(nums, dens, outp);
}

// Round 4
// 2677.905 us; speedup vs baseline: 4.9807x; 2.0897x over previous
//
#include <hip/hip_runtime.h>
#include <stdint.h>

#define TSEQ 512
#define NB   64
#define EMB  300
#define HID  300
#define G4   1200
#define KKP  150     // pairs of K (300/2)
#define NT   9
#define MTOT (TSEQ*NB)   // 32768

// MFMA lstm geometry
#define NP 19          // hid blocks of 16 (covers 304, last block padded)
#define NQ 4           // batch groups of 16
#define NWG (2*NQ*NP)  // 152 workgroups
#define KSTEPS 10      // K padded to 320 = 10 * 32
#define H2STR 20       // padded LDS row stride (dwords): 16B-aligned, 2-way banks

typedef _Float16 h2v __attribute__((ext_vector_type(2)));
typedef _Float16 f16x8 __attribute__((ext_vector_type(8)));
typedef float f32x4 __attribute__((ext_vector_type(4)));
union H2U { uint32_t u; h2v h; };

__device__ __forceinline__ float dot2f(uint32_t a, uint32_t b, float c) {
#if __has_builtin(__builtin_amdgcn_fdot2)
  H2U ua; ua.u = a; H2U ub; ub.u = b;
  return __builtin_amdgcn_fdot2(ua.h, ub.h, c, false);
#else
  H2U ua; ua.u = a; H2U ub; ub.u = b;
  return c + (float)ua.h.x*(float)ub.h.x + (float)ua.h.y*(float)ub.h.y;
#endif
}

__device__ __forceinline__ uint32_t packf2(float a, float b) {
  H2U u; u.h.x = (_Float16)a; u.h.y = (_Float16)b; return u.u;
}

__device__ __forceinline__ float sigm(float x) { return 1.0f / (1.0f + expf(-x)); }

// ---- pack W_ih (f32 [1200][300]) into f16x2 [150][1200] for embed_pre ----
__global__ __launch_bounds__(256) void prep_wih(
    const float* __restrict__ Wihf, const float* __restrict__ Wihb,
    uint32_t* __restrict__ wtih) {
  int i = blockIdx.x * 256 + threadIdx.x;
  if (i >= KKP * G4) return;
  int m = blockIdx.y;  // 0:ih_f 1:ih_b
  int kk = i / G4, g = i % G4;
  const float* src = (m == 0) ? Wihf : Wihb;
  float2 v = *(const float2*)(src + (size_t)g * 300 + 2 * kk);
  wtih[(size_t)m * (KKP * G4) + i] = packf2(v.x, v.y);
}

__global__ __launch_bounds__(256) void prep_bias(
    const float* __restrict__ bihf, const float* __restrict__ bhhf,
    const float* __restrict__ bihb, const float* __restrict__ bhhb,
    float* __restrict__ bias) {
  int i = blockIdx.x * 256 + threadIdx.x;
  if (i < G4) {
    bias[i]       = bihf[i] + bhhf[i];
    bias[G4 + i]  = bihb[i] + bhhb[i];
  }
}

// ---- pack W_hh into per-lane MFMA A-fragments ----
// blk = ((d*NP + p)*4 + gamma)*KSTEPS + ks ; 64 threads = lanes.
// A-frag layout (16x16x32 f16): lane l holds A[row = l&15][k = (l>>4)*8 + e], e=0..7,
// packed as 4 dwords of f16-pairs (k even, k odd).
__global__ __launch_bounds__(64) void prep_w2(
    const float* __restrict__ Whhf, const float* __restrict__ Whhb,
    uint32_t* __restrict__ w2) {
  int blk = blockIdx.x;
  int ks = blk % KSTEPS; int tmp = blk / KSTEPS;
  int gamma = tmp & 3; tmp >>= 2;
  int p = tmp % NP; int d = tmp / NP;
  int lane = threadIdx.x;
  const float* W = d ? Whhb : Whhf;
  int hid = 16 * p + (lane & 15);
  int k0 = ks * 32 + (lane >> 4) * 8;
  float vals[8];
  #pragma unroll
  for (int e = 0; e < 8; ++e) {
    int k = k0 + e;
    vals[e] = (hid < 300 && k < 300) ? W[(size_t)(gamma * 300 + hid) * 300 + k] : 0.0f;
  }
  uint4 dw;
  dw.x = packf2(vals[0], vals[1]);
  dw.y = packf2(vals[2], vals[3]);
  dw.z = packf2(vals[4], vals[5]);
  dw.w = packf2(vals[6], vals[7]);
  *(uint4*)(w2 + ((size_t)blk * 64 + lane) * 4) = dw;
}

// ---- zero sync flags + h2 double buffer (must run every launch) ----
__global__ __launch_bounds__(256) void init_sync(
    uint32_t* __restrict__ flags, uint32_t* __restrict__ h2g) {
  int i = blockIdx.x * 256 + threadIdx.x;
  if (i < 256) flags[i] = 0;
  if (i < 2 * 2 * 160 * 64) h2g[i] = 0;
}

// ---- gather embeddings -> packed f16x2, layout Ae[kk][m] (m = t*64+b) ----
__global__ __launch_bounds__(256) void gather_emb(
    const int* __restrict__ x, const float* __restrict__ emb,
    uint32_t* __restrict__ Ae) {
  __shared__ __align__(16) uint32_t buf[64 * KKP];
  __shared__ int idxs[64];
  int tid = threadIdx.x;
  int m0 = blockIdx.x * 64;
  if (tid < 64) {
    int mm = m0 + tid;
    idxs[tid] = x[(size_t)(mm & 63) * TSEQ + (mm >> 6)];   // x[b][t]
  }
  __syncthreads();
  for (int i = tid; i < 64 * KKP; i += 256) {
    int mm = i / KKP, kk = i % KKP;
    float2 v = *(const float2*)(emb + (size_t)idxs[mm] * EMB + 2 * kk);
    buf[i] = packf2(v.x, v.y);
  }
  __syncthreads();
  for (int i = tid; i < 64 * KKP; i += 256) {
    int kk = i >> 6, mm = i & 63;
    Ae[(size_t)kk * MTOT + m0 + mm] = buf[mm * KKP + kk];
  }
}

// ---- pre = emb @ W_ih^T + (b_ih+b_hh), stored f16 [2][32768][1200] ----
__global__ __launch_bounds__(256) void embed_pre(
    const uint32_t* __restrict__ Ae, const uint32_t* __restrict__ wtih,
    const float* __restrict__ bias, _Float16* __restrict__ pre) {
  int d = blockIdx.z;
  int m0 = blockIdx.x * 64, n0 = blockIdx.y * 64;
  int tid = threadIdx.x;
  __shared__ __align__(16) uint32_t As[30 * 64];
  __shared__ __align__(16) uint32_t Bs[30 * 64];
  const uint32_t* W = wtih + (size_t)d * (KKP * G4);
  int tx = tid & 15, ty = tid >> 4;
  float acc[4][4] = {};
  for (int c = 0; c < 5; ++c) {
    int kb = c * 30;
    for (int i = tid; i < 30 * 64; i += 256) {
      int kk = i >> 6, mm = i & 63;
      As[i] = Ae[(size_t)(kb + kk) * MTOT + m0 + mm];
    }
    for (int i = tid; i < 30 * 64; i += 256) {
      int kk = i >> 6, cc = i & 63;
      int g = n0 + cc;
      Bs[i] = (g < G4) ? W[(size_t)(kb + kk) * G4 + g] : 0u;
    }
    __syncthreads();
    #pragma unroll 5
    for (int kk = 0; kk < 30; ++kk) {
      uint4 a4 = *(const uint4*)&As[kk * 64 + ty * 4];
      uint4 b4 = *(const uint4*)&Bs[kk * 64 + tx * 4];
      uint32_t av[4] = {a4.x, a4.y, a4.z, a4.w};
      uint32_t bv[4] = {b4.x, b4.y, b4.z, b4.w};
      #pragma unroll
      for (int im = 0; im < 4; ++im)
        #pragma unroll
        for (int in = 0; in < 4; ++in)
          acc[im][in] = dot2f(av[im], bv[in], acc[im][in]);
    }
    __syncthreads();
  }
  #pragma unroll
  for (int im = 0; im < 4; ++im) {
    int mm = m0 + ty * 4 + im;
    #pragma unroll
    for (int in = 0; in < 4; ++in) {
      int g = n0 + tx * 4 + in;
      if (g < G4)
        pre[((size_t)d * MTOT + mm) * G4 + g] = (_Float16)(acc[im][in] + bias[d * G4 + g]);
    }
  }
}

// ---- MFMA LSTM: WG = (dir d, batch-group q of 16, hid-block p of 16) ----
// Wave gamma computes gate gamma's 16x16 tile; weights live in registers.
// Sync protocol (cheap): relaxed polls, ONE acquire fence per step (wave 0),
// plain vectorized h2 loads (fence guarantees no stale L1/L2 serve),
// relaxed flag store after __syncthreads (its vmcnt(0) drain = release).
__global__ __launch_bounds__(256) void lstm_mfma(
    const uint32_t* __restrict__ w2, const _Float16* __restrict__ pre,
    uint32_t* __restrict__ h2g, uint32_t* __restrict__ flags,
    float* __restrict__ hs) {
  const int wg = blockIdx.x;           // ((d*NQ+q)*NP + p)
  const int p  = wg % NP;
  const int dq = wg / NP;
  const int q  = dq % NQ;
  const int d  = dq / NQ;
  const int tid = threadIdx.x;
  const int gamma = tid >> 6;          // wave = gate
  const int lane  = tid & 63;

  __shared__ __align__(16) uint32_t h2L[160 * H2STR];   // [kk][col], stride 20
  __shared__ float gateL[4 * 16 * H2STR];               // [gate*16+row][col]

  for (int i = tid; i < 160 * H2STR; i += 256) h2L[i] = 0u;  // rows>=150 stay 0

  // preload A fragments (weights) into registers: 10 ksteps x uint4
  uint4 afr[KSTEPS];
  const int blk0 = ((d * NP + p) * 4 + gamma) * KSTEPS;
  #pragma unroll
  for (int ks = 0; ks < KSTEPS; ++ks)
    afr[ks] = *(const uint4*)(w2 + (size_t)(blk0 + ks) * 256 + lane * 4);

  // cell-update mapping: thread -> (hid-local, batch-local)
  const int hidl = tid >> 4;
  const int bl = tid & 15;
  const int hid = 16 * p + hidl;
  const int bglob = 16 * q + bl;
  float cstate = 0.0f;

  // acc/pre mapping: lane covers rows rowh0..rowh0+3, col = batch (lane&15)
  const int rowh0 = 16 * p + ((lane >> 4) * 4);
  const bool rowok = rowh0 < 300;
  const int bpre = 16 * q + (lane & 15);

  const uint32_t* fl = flags + (d * NQ + q) * NP;  // group's 19 flags
  uint32_t* myflag = flags + wg;

  __syncthreads();

  for (int s = 0; s < TSEQ; ++s) {
    const int t = d ? (TSEQ - 1 - s) : s;

    // prefetch pre slice (independent of h) before the poll
    uint2 pr = make_uint2(0u, 0u);
    if (rowok)
      pr = *(const uint2*)(pre + ((size_t)d * MTOT + (size_t)t * NB + bpre) * G4
                           + (gamma * 300 + rowh0));

    // wait: all group members published step s-1 (flag >= s). RELAXED polls.
    if (s > 0 && tid < 64) {
      bool done = false;
      while (!done) {
        uint32_t v = 0xFFFFFFFFu;
        if (lane < NP)
          v = __hip_atomic_load(fl + lane, __ATOMIC_RELAXED, __HIP_MEMORY_SCOPE_AGENT);
        done = __all((int)(v >= (uint32_t)s));
      }
      // one invalidate per step: make peers' MALL data visible to plain loads
      __builtin_amdgcn_fence(__ATOMIC_ACQUIRE, "agent");
    }
    __syncthreads();

    // load h(s-1) from parity buffer into LDS: 150 rows x 16 cols, uint4 chunks
    {
      const uint32_t* src = h2g + (size_t)(((s + 1) & 1) * 2 + d) * 160 * 64 + 16 * q;
      for (int i = tid; i < KKP * 4; i += 256) {
        int kk = i >> 2, c4 = i & 3;
        uint4 v = *(const uint4*)(src + kk * 64 + c4 * 4);
        *(uint4*)&h2L[kk * H2STR + c4 * 4] = v;
      }
    }
    __syncthreads();

    // acc = pre (bias already folded in), then 10 MFMAs over K=320
    f32x4 acc;
    {
      union { uint2 u; _Float16 h[4]; } cv; cv.u = pr;
      acc[0] = (float)cv.h[0]; acc[1] = (float)cv.h[1];
      acc[2] = (float)cv.h[2]; acc[3] = (float)cv.h[3];
    }
    #pragma unroll
    for (int ks = 0; ks < KSTEPS; ++ks) {
      union { uint32_t u[4]; f16x8 v; } bu;
      int base = (ks * 16 + (lane >> 4) * 4) * H2STR + (lane & 15);
      bu.u[0] = h2L[base];
      bu.u[1] = h2L[base + H2STR];
      bu.u[2] = h2L[base + 2 * H2STR];
      bu.u[3] = h2L[base + 3 * H2STR];
      union { uint4 u; f16x8 v; } au; au.u = afr[ks];
      acc = __builtin_amdgcn_mfma_f32_16x16x32_f16(au.v, bu.v, acc, 0, 0, 0);
    }

    // exchange gates through LDS: D layout row=(lane>>4)*4+r, col=lane&15
    {
      int rbase = (lane >> 4) * 4, col = lane & 15;
      #pragma unroll
      for (int r = 0; r < 4; ++r)
        gateL[(gamma * 16 + rbase + r) * H2STR + col] = acc[r];
    }
    __syncthreads();

    // cell update (c stays in this thread's register for all 512 steps)
    float gi = gateL[(0 * 16 + hidl) * H2STR + bl];
    float gf = gateL[(1 * 16 + hidl) * H2STR + bl];
    float gg = gateL[(2 * 16 + hidl) * H2STR + bl];
    float go = gateL[(3 * 16 + hidl) * H2STR + bl];
    float iv = sigm(gi), fv = sigm(gf), gv = tanhf(gg), ov = sigm(go);
    cstate = fv * cstate + iv * gv;
    float h = ov * tanhf(cstate);

    if (hid < 300)
      hs[((size_t)d * MTOT + (size_t)t * NB + bglob) * HID + hid] = h;

    // publish packed h pair (hid even thread packs with hid+1 via shfl)
    float hpart = __shfl_xor(h, 16);
    if ((hidl & 1) == 0 && hid < 300) {
      uint32_t dw = packf2(h, hpart);
      int kk = 8 * p + (hidl >> 1);
      uint32_t* dst = h2g + ((size_t)((s & 1) * 2 + d) * 160 + kk) * 64 + bglob;
      __hip_atomic_store(dst, dw, __ATOMIC_RELAXED, __HIP_MEMORY_SCOPE_AGENT);
    }
    __syncthreads();   // vmcnt(0) drain: all h2 stores at MALL before flag
    if (tid == 0)
      __hip_atomic_store(myflag, (uint32_t)(s + 1), __ATOMIC_RELAXED,
                         __HIP_MEMORY_SCOPE_AGENT);
  }
}

// ---- logits = [h_f,h_b] @ W_lin^T + b_lin ; probs = softmax ----
__global__ __launch_bounds__(256) void logits_probs(
    const float* __restrict__ hs, const float* __restrict__ Wlin,
    const float* __restrict__ blin, float* __restrict__ probs) {
  __shared__ float Ws[NT * 600];
  __shared__ float bs[NT];
  int tid = threadIdx.x;
  for (int i = tid; i < NT * 600; i += 256) Ws[i] = Wlin[i];
  if (tid < NT) bs[tid] = blin[tid];
  __syncthreads();
  int wave = tid >> 6, lane = tid & 63;
  int tb = blockIdx.x * 4 + wave;     // = t*64 + b
  const float* hf = hs + (size_t)tb * HID;
  const float* hb = hs + ((size_t)MTOT + tb) * HID;
  float p[NT];
  #pragma unroll
  for (int k = 0; k < NT; ++k) p[k] = 0.f;
  for (int e = lane; e < HID; e += 64) {
    float vf = hf[e], vb = hb[e];
    #pragma unroll
    for (int k = 0; k < NT; ++k)
      p[k] += vf * Ws[k * 600 + e] + vb * Ws[k * 600 + 300 + e];
  }
  #pragma unroll
  for (int off = 32; off > 0; off >>= 1)
    #pragma unroll
    for (int k = 0; k < NT; ++k) p[k] += __shfl_xor(p[k], off);
  float l[NT]; float mx = -1e30f;
  #pragma unroll
  for (int k = 0; k < NT; ++k) { l[k] = p[k] + bs[k]; mx = fmaxf(mx, l[k]); }
  float ssum = 0.f;
  #pragma unroll
  for (int k = 0; k < NT; ++k) ssum = ssum + expf(l[k] - mx);
  int t = tb >> 6, b = tb & 63;
  if (lane < NT)
    probs[((size_t)b * TSEQ + t) * NT + lane] = expf(l[lane] - mx) / ssum;
}

// ---- CRF numerator per batch ----
__global__ __launch_bounds__(256) void crf_num(
    const int* __restrict__ y, const float* __restrict__ probs,
    const float* __restrict__ strt, const float* __restrict__ endt,
    const float* __restrict__ trans, float* __restrict__ nums) {
  int b = blockIdx.x, tid = threadIdx.x;
  __shared__ float r1[256], r2[256];
  float s = 0.f, cnt = 0.f;
  for (int t = tid; t < TSEQ; t += 256) {
    int yc = y[(size_t)b * TSEQ + t];
    cnt += (yc != -1) ? 1.f : 0.f;
    if (t >= 1) {
      int yp = y[(size_t)b * TSEQ + t - 1];
      float mask = (yc != -1) ? 1.f : 0.f;
      s += mask * (trans[yp * NT + yc] + probs[((size_t)b * TSEQ + t) * NT + yc]);
    }
  }
  r1[tid] = s; r2[tid] = cnt;
  __syncthreads();
  for (int off = 128; off > 0; off >>= 1) {
    if (tid < off) { r1[tid] += r1[tid + off]; r2[tid] += r2[tid + off]; }
    __syncthreads();
  }
  if (tid == 0) {
    int y0 = y[(size_t)b * TSEQ];
    int seqlen = (int)(r2[0] + 0.5f);
    int ylast = y[(size_t)b * TSEQ + seqlen - 1];
    nums[b] = strt[y0] + probs[((size_t)b * TSEQ) * NT + y0] + r1[0] + endt[ylast];
  }
}

// ---- CRF forward algorithm (denominator) per batch ----
__global__ __launch_bounds__(64) void crf_alpha(
    const int* __restrict__ y, const float* __restrict__ probs,
    const float* __restrict__ strt, const float* __restrict__ endt,
    const float* __restrict__ trans, float* __restrict__ dens) {
  int b = blockIdx.x, lane = threadIdx.x;
  __shared__ float tr[NT * NT];
  __shared__ float al[NT];
  if (lane < NT * NT) tr[lane] = trans[lane];
  if (lane < NT) al[lane] = strt[lane] + probs[((size_t)b * TSEQ) * NT + lane];
  __syncthreads();
  for (int t = 1; t < TSEQ; ++t) {
    float nxt = 0.f;
    int m = (y[(size_t)b * TSEQ + t] != -1);
    if (lane < NT) {
      float e = probs[((size_t)b * TSEQ + t) * NT + lane];
      float mx = -1e30f;
      #pragma unroll
      for (int j = 0; j < NT; ++j) mx = fmaxf(mx, al[j] + tr[j * NT + lane]);
      float sum = 0.f;
      #pragma unroll
      for (int j = 0; j < NT; ++j) sum += expf(al[j] + tr[j * NT + lane] - mx);
      nxt = e + mx + logf(sum);
    }
    __syncthreads();
    if (lane < NT && m) al[lane] = nxt;
    __syncthreads();
  }
  if (lane == 0) {
    float mx = -1e30f;
    for (int k = 0; k < NT; ++k) mx = fmaxf(mx, al[k] + endt[k]);
    float sum = 0.f;
    for (int k = 0; k < NT; ++k) sum += expf(al[k] + endt[k] - mx);
    dens[b] = mx + logf(sum);
  }
}

__global__ __launch_bounds__(64) void final_sum(
    const float* __restrict__ nums, const float* __restrict__ dens,
    float* __restrict__ out) {
  __shared__ float r[64];
  int tid = threadIdx.x;
  r[tid] = nums[tid] - dens[tid];
  __syncthreads();
  for (int off = 32; off > 0; off >>= 1) {
    if (tid < off) r[tid] += r[tid + off];
    __syncthreads();
  }
  if (tid == 0) out[(size_t)MTOT * NT] = -r[0];
}

extern "C" void kernel_launch(void* const* d_in, const int* in_sizes, int n_in,
                              void* d_out, int out_size, void* d_ws, size_t ws_size,
                              hipStream_t stream) {
  (void)in_sizes; (void)n_in; (void)out_size;
  const int*   x     = (const int*)d_in[0];
  const int*   y     = (const int*)d_in[1];
  const float* emb   = (const float*)d_in[2];
  const float* Wihf  = (const float*)d_in[3];
  const float* Whhf  = (const float*)d_in[4];
  const float* bihf  = (const float*)d_in[5];
  const float* bhhf  = (const float*)d_in[6];
  const float* Wihb  = (const float*)d_in[7];
  const float* Whhb  = (const float*)d_in[8];
  const float* bihb  = (const float*)d_in[9];
  const float* bhhb  = (const float*)d_in[10];
  const float* Wlin  = (const float*)d_in[11];
  const float* blin  = (const float*)d_in[12];
  const float* strt  = (const float*)d_in[13];
  const float* endt  = (const float*)d_in[14];
  const float* trans = (const float*)d_in[15];
  float* outp = (float*)d_out;

  char* ws = (char*)d_ws;
  const size_t OFF_WTIH  = 0;            // 1,440,000
  const size_t OFF_W2    = 1440000;      // 1,556,480
  const size_t OFF_BIAS  = 2996480;      // 9,600
  const size_t OFF_NUMS  = 3006080;      // 256
  const size_t OFF_DENS  = 3006336;      // 256
  const size_t OFF_FLAGS = 3006592;      // 1,024
  const size_t OFF_H2G   = 3007616;      // 163,840
  const size_t OFF_AE    = 3171456;      // 19,660,800
  const size_t OFF_HS    = 22832256;     // 78,643,200
  const size_t OFF_PRE   = 101475456;    // 157,286,400 -> end 258,761,856
  if (ws_size < 258761856ull) return;

  uint32_t* wtih  = (uint32_t*)(ws + OFF_WTIH);
  uint32_t* w2    = (uint32_t*)(ws + OFF_W2);
  float*    bias  = (float*)(ws + OFF_BIAS);
  float*    nums  = (float*)(ws + OFF_NUMS);
  float*    dens  = (float*)(ws + OFF_DENS);
  uint32_t* flags = (uint32_t*)(ws + OFF_FLAGS);
  uint32_t* h2g   = (uint32_t*)(ws + OFF_H2G);
  uint32_t* Ae    = (uint32_t*)(ws + OFF_AE);
  float*    hsb   = (float*)(ws + OFF_HS);
  _Float16* pre   = (_Float16*)(ws + OFF_PRE);

  prep_wih<<<dim3((KKP * G4 + 255) / 256, 2), 256, 0, stream>>>(Wihf, Wihb, wtih);
  prep_bias<<<dim3((G4 + 255) / 256), 256, 0, stream>>>(bihf, bhhf, bihb, bhhb, bias);
  prep_w2<<<dim3(2 * NP * 4 * KSTEPS), 64, 0, stream>>>(Whhf, Whhb, w2);
  init_sync<<<dim3(160), 256, 0, stream>>>(flags, h2g);
  gather_emb<<<dim3(MTOT / 64), 256, 0, stream>>>(x, emb, Ae);
  embed_pre<<<dim3(MTOT / 64, (G4 + 63) / 64, 2), 256, 0, stream>>>(Ae, wtih, bias, pre);
  lstm_mfma<<<dim3(NWG), 256, 0, stream>>>(w2, pre, h2g, flags, hsb);
  logits_probs<<<dim3(MTOT / 4), 256, 0, stream>>>(hsb, Wlin, blin, outp);
  crf_num<<<dim3(NB), 256, 0, stream>>>(y, outp, strt, endt, trans, nums);
  crf_alpha<<<dim3(NB), 64, 0, stream>>>(y, outp, strt, endt, trans, dens);
  final_sum<<<1, 64, 0, stream>>>(nums, dens, outp);
}

// Round 5
// 2004.010 us; speedup vs baseline: 6.6555x; 1.3363x over previous
//
#include <hip/hip_runtime.h>
#include <stdint.h>

#define TSEQ 512
#define NB   64
#define EMB  300
#define HID  300
#define G4   1200
#define KKP  150     // pairs of K (300/2)
#define NT   9
#define MTOT (TSEQ*NB)   // 32768

// MFMA lstm geometry
#define NP 19          // hid blocks of 16 (covers 304, last block padded)
#define NQ 4           // batch groups of 16
#define NWG (2*NQ*NP)  // 152 workgroups
#define KSTEPS 10      // K padded to 320 = 10 * 32
#define HROWS 160      // h2g rows (k-pairs), rows 150..159 stay zero

typedef _Float16 h2v __attribute__((ext_vector_type(2)));
typedef _Float16 f16x8 __attribute__((ext_vector_type(8)));
typedef float f32x4 __attribute__((ext_vector_type(4)));
union H2U { uint32_t u; h2v h; };

__device__ __forceinline__ uint32_t packf2(float a, float b) {
  H2U u; u.h.x = (_Float16)a; u.h.y = (_Float16)b; return u.u;
}

__device__ __forceinline__ float sigm(float x) { return 1.0f / (1.0f + expf(-x)); }

// ---- pack W_ih (f32 [1200][300]) into f16x2 [150][1200] ----
__global__ __launch_bounds__(256) void prep_wih(
    const float* __restrict__ Wihf, const float* __restrict__ Wihb,
    uint32_t* __restrict__ wtih) {
  int i = blockIdx.x * 256 + threadIdx.x;
  if (i >= KKP * G4) return;
  int m = blockIdx.y;  // 0:ih_f 1:ih_b
  int kk = i / G4, g = i % G4;
  const float* src = (m == 0) ? Wihf : Wihb;
  float2 v = *(const float2*)(src + (size_t)g * 300 + 2 * kk);
  wtih[(size_t)m * (KKP * G4) + i] = packf2(v.x, v.y);
}

__global__ __launch_bounds__(256) void prep_bias(
    const float* __restrict__ bihf, const float* __restrict__ bhhf,
    const float* __restrict__ bihb, const float* __restrict__ bhhb,
    float* __restrict__ bias) {
  int i = blockIdx.x * 256 + threadIdx.x;
  if (i < G4) {
    bias[i]       = bihf[i] + bhhf[i];
    bias[G4 + i]  = bihb[i] + bhhb[i];
  }
}

// ---- pack W_hh into per-lane MFMA A-fragments, gates stacked in M ----
// blk = ((d*NP + p)*4 + w)*KSTEPS + ks.  A row m = l&15 -> (gamma=m>>2, rr=m&3),
// W_hh row = gamma*300 + 16p + 4w + rr ; k = ks*32 + (l>>4)*8 + e.
__global__ __launch_bounds__(64) void prep_w3(
    const float* __restrict__ Whhf, const float* __restrict__ Whhb,
    uint32_t* __restrict__ w2) {
  int blk = blockIdx.x;
  int ks = blk % KSTEPS; int tmp = blk / KSTEPS;
  int w = tmp & 3; tmp >>= 2;
  int p = tmp % NP; int d = tmp / NP;
  int lane = threadIdx.x;
  const float* W = d ? Whhb : Whhf;
  int m = lane & 15;
  int gamma = m >> 2, rr = m & 3;
  int hid = 16 * p + 4 * w + rr;
  int k0 = ks * 32 + (lane >> 4) * 8;
  float vals[8];
  #pragma unroll
  for (int e = 0; e < 8; ++e) {
    int k = k0 + e;
    vals[e] = (hid < 300 && k < 300) ? W[(size_t)(gamma * 300 + hid) * 300 + k] : 0.0f;
  }
  uint4 dw;
  dw.x = packf2(vals[0], vals[1]);
  dw.y = packf2(vals[2], vals[3]);
  dw.z = packf2(vals[4], vals[5]);
  dw.w = packf2(vals[6], vals[7]);
  *(uint4*)(w2 + ((size_t)blk * 64 + lane) * 4) = dw;
}

// ---- zero per-wave flags + h2 double buffer (every launch: graph replay) ----
__global__ __launch_bounds__(256) void init_sync(
    uint32_t* __restrict__ flags, uint32_t* __restrict__ h2g) {
  int i = blockIdx.x * 256 + threadIdx.x;
  if (i < 8 * 128) flags[i] = 0;
  if (i < 2 * 2 * HROWS * 64) h2g[i] = 0;
}

// ---- gather embeddings -> packed f16x2, layout Ae[kk][m] (m = t*64+b) ----
__global__ __launch_bounds__(256) void gather_emb(
    const int* __restrict__ x, const float* __restrict__ emb,
    uint32_t* __restrict__ Ae) {
  __shared__ __align__(16) uint32_t buf[64 * KKP];
  __shared__ int idxs[64];
  int tid = threadIdx.x;
  int m0 = blockIdx.x * 64;
  if (tid < 64) {
    int mm = m0 + tid;
    idxs[tid] = x[(size_t)(mm & 63) * TSEQ + (mm >> 6)];   // x[b][t]
  }
  __syncthreads();
  for (int i = tid; i < 64 * KKP; i += 256) {
    int mm = i / KKP, kk = i % KKP;
    float2 v = *(const float2*)(emb + (size_t)idxs[mm] * EMB + 2 * kk);
    buf[i] = packf2(v.x, v.y);
  }
  __syncthreads();
  for (int i = tid; i < 64 * KKP; i += 256) {
    int kk = i >> 6, mm = i & 63;
    Ae[(size_t)kk * MTOT + m0 + mm] = buf[mm * KKP + kk];
  }
}

// ---- pre = emb @ W_ih^T + bias via MFMA. WG: 128 m x 64 n; wave: 16n, 8 m-subtiles ----
__global__ __launch_bounds__(256) void embed_pre_mfma(
    const uint32_t* __restrict__ Ae, const uint32_t* __restrict__ wtih,
    const float* __restrict__ bias, _Float16* __restrict__ pre) {
  const int d = blockIdx.z;
  const int tid = threadIdx.x;
  const int w = tid >> 6, lane = tid & 63;
  const int n0 = blockIdx.x * 64 + w * 16;
  const int m00 = blockIdx.y * 128;
  const int col = n0 + (lane & 15);
  const bool colok = col < G4;
  const int rsel = lane >> 4;
  const uint32_t* Wd = wtih + (size_t)d * (KKP * G4);
  uint32_t bfr[KSTEPS][4];
  #pragma unroll
  for (int ks = 0; ks < KSTEPS; ++ks)
    #pragma unroll
    for (int j = 0; j < 4; ++j) {
      int kk = ks * 16 + rsel * 4 + j;
      bfr[ks][j] = (kk < KKP && colok) ? Wd[(size_t)kk * G4 + col] : 0u;
    }
  float bcol = colok ? bias[d * G4 + col] : 0.0f;
  for (int mb = 0; mb < 8; ++mb) {
    const int m0 = m00 + mb * 16;
    uint32_t afr[KSTEPS][4];
    #pragma unroll
    for (int ks = 0; ks < KSTEPS; ++ks)
      #pragma unroll
      for (int j = 0; j < 4; ++j) {
        int kk = ks * 16 + rsel * 4 + j;
        afr[ks][j] = (kk < KKP) ? Ae[(size_t)kk * MTOT + m0 + (lane & 15)] : 0u;
      }
    f32x4 acc; acc[0] = bcol; acc[1] = bcol; acc[2] = bcol; acc[3] = bcol;
    #pragma unroll
    for (int ks = 0; ks < KSTEPS; ++ks) {
      union { uint32_t u[4]; f16x8 v; } au, bu;
      au.u[0] = afr[ks][0]; au.u[1] = afr[ks][1]; au.u[2] = afr[ks][2]; au.u[3] = afr[ks][3];
      bu.u[0] = bfr[ks][0]; bu.u[1] = bfr[ks][1]; bu.u[2] = bfr[ks][2]; bu.u[3] = bfr[ks][3];
      acc = __builtin_amdgcn_mfma_f32_16x16x32_f16(au.v, bu.v, acc, 0, 0, 0);
    }
    if (colok) {
      #pragma unroll
      for (int j = 0; j < 4; ++j) {
        int m = m0 + rsel * 4 + j;
        pre[((size_t)d * MTOT + m) * G4 + col] = (_Float16)acc[j];
      }
    }
  }
}

// ---- barrier-free MFMA LSTM ----
// WG = (d, q, p); wave w owns hid rows [16p+4w, +4) for ALL 4 gates (gates in M-dim).
// Per-wave flags; h exchanged via MALL (sc1 relaxed atomics); no __syncthreads in loop.
__global__ __launch_bounds__(256) void lstm_mfma(
    const uint32_t* __restrict__ w2, const _Float16* __restrict__ pre,
    uint32_t* __restrict__ h2g, uint32_t* __restrict__ hs16,
    uint32_t* __restrict__ flags) {
  const int wg = blockIdx.x;           // ((d*NQ+q)*NP + p)
  const int p  = wg % NP;
  const int dq = wg / NP;
  const int q  = dq & 3;
  const int d  = dq >> 2;
  const int tid = threadIdx.x;
  const int w = tid >> 6;
  const int lane = tid & 63;
  const int G = lane >> 4;             // 0..3 (gate group / k-subrange / row-sel)
  const int b = lane & 15;             // batch-local
  const int hidbase = 16 * p + 4 * w;  // this wave's 4 hid rows
  const bool valid = hidbase < 300;    // (p=18,w=3) wave is padding

  __shared__ float xch[4 * 256];       // per-wave 4x4 gate transpose buffer

  // A fragments in registers (10 x uint4)
  uint4 afr[KSTEPS];
  const int blk0 = ((d * NP + p) * 4 + w) * KSTEPS;
  #pragma unroll
  for (int ks = 0; ks < KSTEPS; ++ks)
    afr[ks] = *(const uint4*)(w2 + (size_t)(blk0 + ks) * 256 + (size_t)lane * 4);

  uint32_t* flagbase = flags + dq * 128;
  uint32_t* myflag = flagbase + p * 4 + w;
  float cstate = 0.0f;

  for (int s = 0; s < TSEQ; ++s) {
    const int t = d ? (TSEQ - 1 - s) : s;

    // prefetch pre slice (plain cacheable load), consumed after poll
    uint2 pr = make_uint2(0u, 0u);
    if (valid)
      pr = *(const uint2*)(pre + ((size_t)d * MTOT + (size_t)t * NB + 16 * q + b) * G4
                           + (G * 300 + hidbase));

    // poll the group's 76 per-wave flags (relaxed, MALL-direct)
    if (s > 0) {
      const uint32_t sv = (uint32_t)s;
      for (;;) {
        uint32_t v0 = __hip_atomic_load(flagbase + lane, __ATOMIC_RELAXED,
                                        __HIP_MEMORY_SCOPE_AGENT);
        uint32_t v1 = sv;
        if (lane < 12)
          v1 = __hip_atomic_load(flagbase + 64 + lane, __ATOMIC_RELAXED,
                                 __HIP_MEMORY_SCOPE_AGENT);
        if (__all((int)(v0 >= sv && v1 >= sv))) break;
      }
      asm volatile("" ::: "memory");   // compile-time fence: keep loads below
    }

    // B fragments straight from MALL (sc1 relaxed): 40 dwords
    const uint32_t* hb = h2g + (size_t)(((s + 1) & 1) * 2 + d) * (HROWS * 64)
                         + 16 * q + b;
    uint32_t bf[KSTEPS][4];
    #pragma unroll
    for (int ks = 0; ks < KSTEPS; ++ks)
      #pragma unroll
      for (int j = 0; j < 4; ++j)
        bf[ks][j] = __hip_atomic_load(hb + (size_t)(ks * 16 + G * 4 + j) * 64,
                                      __ATOMIC_RELAXED, __HIP_MEMORY_SCOPE_AGENT);

    // two independent MFMA chains (halve dependency latency)
    f32x4 acc0, acc1;
    {
      union { uint2 u; _Float16 h[4]; } cv; cv.u = pr;
      acc0[0] = (float)cv.h[0]; acc0[1] = (float)cv.h[1];
      acc0[2] = (float)cv.h[2]; acc0[3] = (float)cv.h[3];
      acc1[0] = 0.f; acc1[1] = 0.f; acc1[2] = 0.f; acc1[3] = 0.f;
    }
    #pragma unroll
    for (int ks = 0; ks < KSTEPS; ks += 2) {
      union { uint4 u; f16x8 v; } au0, au1;
      union { uint32_t u[4]; f16x8 v; } bu0, bu1;
      au0.u = afr[ks]; au1.u = afr[ks + 1];
      bu0.u[0] = bf[ks][0]; bu0.u[1] = bf[ks][1]; bu0.u[2] = bf[ks][2]; bu0.u[3] = bf[ks][3];
      bu1.u[0] = bf[ks+1][0]; bu1.u[1] = bf[ks+1][1]; bu1.u[2] = bf[ks+1][2]; bu1.u[3] = bf[ks+1][3];
      acc0 = __builtin_amdgcn_mfma_f32_16x16x32_f16(au0.v, bu0.v, acc0, 0, 0, 0);
      acc1 = __builtin_amdgcn_mfma_f32_16x16x32_f16(au1.v, bu1.v, acc1, 0, 0, 0);
    }
    // acc[j]: lane (G,b) holds gate G, hid row hidbase+j, batch 16q+b
    // in-wave 4x4 transpose (rr x gate) via LDS, wave-synchronous
    #pragma unroll
    for (int j = 0; j < 4; ++j)
      xch[w * 256 + (j * 4 + G) * 16 + b] = acc0[j] + acc1[j];
    asm volatile("s_waitcnt lgkmcnt(0)" ::: "memory");
    float gi = xch[w * 256 + (G * 4 + 0) * 16 + b];
    float gf = xch[w * 256 + (G * 4 + 1) * 16 + b];
    float gg = xch[w * 256 + (G * 4 + 2) * 16 + b];
    float go = xch[w * 256 + (G * 4 + 3) * 16 + b];

    // cell update for row hidbase+G, batch 16q+b (c stays in register)
    float iv = sigm(gi), fv = sigm(gf), gv = tanhf(gg), ov = sigm(go);
    cstate = fv * cstate + iv * gv;
    float h = ov * tanhf(cstate);

    // pack pairs (rows even/odd) and publish
    float hp = __shfl_xor(h, 16);      // G0<->G1, G2<->G3
    if (valid && (G & 1) == 0) {
      uint32_t dw = packf2(h, hp);
      int kk = (hidbase + G) >> 1;     // = 8p + 2w + (G>>1), <= 149
      uint32_t* dst = h2g + (size_t)((s & 1) * 2 + d) * (HROWS * 64)
                      + (size_t)kk * 64 + 16 * q + b;
      __hip_atomic_store(dst, dw, __ATOMIC_RELAXED, __HIP_MEMORY_SCOPE_AGENT);
      hs16[((size_t)d * MTOT + (size_t)t * NB + 16 * q + b) * 152 + kk] = dw;
    }
    asm volatile("s_waitcnt vmcnt(0)" ::: "memory");
    if (lane == 0)
      __hip_atomic_store(myflag, (uint32_t)(s + 1), __ATOMIC_RELAXED,
                         __HIP_MEMORY_SCOPE_AGENT);
  }
}

// ---- logits from f16 h pairs; 16 tb per WG; softmax -> probs ----
__global__ __launch_bounds__(256) void logits_probs(
    const uint32_t* __restrict__ hs16, const float* __restrict__ Wlin,
    const float* __restrict__ blin, float* __restrict__ probs) {
  __shared__ float Ws[NT * 600];
  __shared__ float bs[NT];
  int tid = threadIdx.x;
  for (int i = tid; i < NT * 600; i += 256) Ws[i] = Wlin[i];
  if (tid < NT) bs[tid] = blin[tid];
  __syncthreads();
  int wave = tid >> 6, lane = tid & 63;
  for (int it = 0; it < 4; ++it) {
    int tb = blockIdx.x * 16 + wave * 4 + it;
    const uint32_t* hf = hs16 + (size_t)tb * 152;
    const uint32_t* hb = hs16 + ((size_t)MTOT + tb) * 152;
    uint32_t f0 = hf[lane], f1 = hf[64 + lane];
    uint32_t f2 = (lane < 22) ? hf[128 + lane] : 0u;
    uint32_t g0 = hb[lane], g1 = hb[64 + lane];
    uint32_t g2 = (lane < 22) ? hb[128 + lane] : 0u;
    float p[NT];
    #pragma unroll
    for (int k = 0; k < NT; ++k) p[k] = 0.f;
    uint32_t fa[3] = {f0, f1, f2};
    uint32_t ga[3] = {g0, g1, g2};
    #pragma unroll
    for (int c = 0; c < 3; ++c) {
      int kk = c * 64 + lane;
      if (kk < KKP) {
        H2U uf; uf.u = fa[c];
        H2U ug; ug.u = ga[c];
        float hf0 = (float)uf.h.x, hf1 = (float)uf.h.y;
        float hb0 = (float)ug.h.x, hb1 = (float)ug.h.y;
        #pragma unroll
        for (int k = 0; k < NT; ++k)
          p[k] += hf0 * Ws[k * 600 + 2 * kk] + hf1 * Ws[k * 600 + 2 * kk + 1]
                + hb0 * Ws[k * 600 + 300 + 2 * kk] + hb1 * Ws[k * 600 + 300 + 2 * kk + 1];
      }
    }
    #pragma unroll
    for (int off = 32; off > 0; off >>= 1)
      #pragma unroll
      for (int k = 0; k < NT; ++k) p[k] += __shfl_xor(p[k], off);
    float l[NT]; float mx = -1e30f;
    #pragma unroll
    for (int k = 0; k < NT; ++k) { l[k] = p[k] + bs[k]; mx = fmaxf(mx, l[k]); }
    float ssum = 0.f;
    #pragma unroll
    for (int k = 0; k < NT; ++k) ssum += expf(l[k] - mx);
    int t = tb >> 6, bb = tb & 63;
    if (lane < NT)
      probs[((size_t)bb * TSEQ + t) * NT + lane] = expf(l[lane] - mx) / ssum;
  }
}

// ---- CRF numerator per batch ----
__global__ __launch_bounds__(256) void crf_num(
    const int* __restrict__ y, const float* __restrict__ probs,
    const float* __restrict__ strt, const float* __restrict__ endt,
    const float* __restrict__ trans, float* __restrict__ nums) {
  int b = blockIdx.x, tid = threadIdx.x;
  __shared__ float r1[256], r2[256];
  float s = 0.f, cnt = 0.f;
  for (int t = tid; t < TSEQ; t += 256) {
    int yc = y[(size_t)b * TSEQ + t];
    cnt += (yc != -1) ? 1.f : 0.f;
    if (t >= 1) {
      int yp = y[(size_t)b * TSEQ + t - 1];
      float mask = (yc != -1) ? 1.f : 0.f;
      s += mask * (trans[yp * NT + yc] + probs[((size_t)b * TSEQ + t) * NT + yc]);
    }
  }
  r1[tid] = s; r2[tid] = cnt;
  __syncthreads();
  for (int off = 128; off > 0; off >>= 1) {
    if (tid < off) { r1[tid] += r1[tid + off]; r2[tid] += r2[tid + off]; }
    __syncthreads();
  }
  if (tid == 0) {
    int y0 = y[(size_t)b * TSEQ];
    int seqlen = (int)(r2[0] + 0.5f);
    int ylast = y[(size_t)b * TSEQ + seqlen - 1];
    nums[b] = strt[y0] + probs[((size_t)b * TSEQ) * NT + y0] + r1[0] + endt[ylast];
  }
}

// ---- CRF forward algorithm: one wave per batch, shfl-based, LDS-staged probs ----
__global__ __launch_bounds__(64) void crf_alpha(
    const int* __restrict__ y, const float* __restrict__ probs,
    const float* __restrict__ strt, const float* __restrict__ endt,
    const float* __restrict__ trans, float* __restrict__ dens) {
  int b = blockIdx.x, lane = threadIdx.x;
  __shared__ float P[TSEQ * NT];
  __shared__ float msk[TSEQ];
  for (int i = lane; i < TSEQ * NT; i += 64) P[i] = probs[(size_t)b * TSEQ * NT + i];
  for (int i = lane; i < TSEQ; i += 64) msk[i] = (y[(size_t)b * TSEQ + i] != -1) ? 1.f : 0.f;
  asm volatile("s_waitcnt lgkmcnt(0) vmcnt(0)" ::: "memory");
  int li = lane < NT ? lane : NT - 1;
  float trc[NT];
  #pragma unroll
  for (int j = 0; j < NT; ++j) trc[j] = trans[j * NT + li];
  float al = strt[li] + P[li];
  for (int t = 1; t < TSEQ; ++t) {
    float e = P[t * NT + li];
    float m = msk[t];
    float tmp[NT]; float mx = -1e30f;
    #pragma unroll
    for (int j = 0; j < NT; ++j) {
      float aj = __shfl(al, j);
      tmp[j] = aj + trc[j];
      mx = fmaxf(mx, tmp[j]);
    }
    float sum = 0.f;
    #pragma unroll
    for (int j = 0; j < NT; ++j) sum += expf(tmp[j] - mx);
    float nxt = e + mx + logf(sum);
    al = (m > 0.5f) ? nxt : al;
  }
  float v = al + endt[li];
  float mx = -1e30f;
  #pragma unroll
  for (int j = 0; j < NT; ++j) mx = fmaxf(mx, __shfl(v, j));
  float sum = 0.f;
  #pragma unroll
  for (int j = 0; j < NT; ++j) sum += expf(__shfl(v, j) - mx);
  if (lane == 0) dens[b] = mx + logf(sum);
}

__global__ __launch_bounds__(64) void final_sum(
    const float* __restrict__ nums, const float* __restrict__ dens,
    float* __restrict__ out) {
  __shared__ float r[64];
  int tid = threadIdx.x;
  r[tid] = nums[tid] - dens[tid];
  __syncthreads();
  for (int off = 32; off > 0; off >>= 1) {
    if (tid < off) r[tid] += r[tid + off];
    __syncthreads();
  }
  if (tid == 0) out[(size_t)MTOT * NT] = -r[0];
}

extern "C" void kernel_launch(void* const* d_in, const int* in_sizes, int n_in,
                              void* d_out, int out_size, void* d_ws, size_t ws_size,
                              hipStream_t stream) {
  (void)in_sizes; (void)n_in; (void)out_size;
  const int*   x     = (const int*)d_in[0];
  const int*   y     = (const int*)d_in[1];
  const float* emb   = (const float*)d_in[2];
  const float* Wihf  = (const float*)d_in[3];
  const float* Whhf  = (const float*)d_in[4];
  const float* bihf  = (const float*)d_in[5];
  const float* bhhf  = (const float*)d_in[6];
  const float* Wihb  = (const float*)d_in[7];
  const float* Whhb  = (const float*)d_in[8];
  const float* bihb  = (const float*)d_in[9];
  const float* bhhb  = (const float*)d_in[10];
  const float* Wlin  = (const float*)d_in[11];
  const float* blin  = (const float*)d_in[12];
  const float* strt  = (const float*)d_in[13];
  const float* endt  = (const float*)d_in[14];
  const float* trans = (const float*)d_in[15];
  float* outp = (float*)d_out;

  char* ws = (char*)d_ws;
  const size_t OFF_WTIH  = 0;            // 1,440,000
  const size_t OFF_W2    = 1440000;      // 1520*64*16 = 1,556,480
  const size_t OFF_BIAS  = 2996480;      // 9,600
  const size_t OFF_NUMS  = 3006080;      // 256
  const size_t OFF_DENS  = 3006336;      // 256
  const size_t OFF_FLAGS = 3006592;      // 4,096
  const size_t OFF_H2G   = 3010688;      // 2*2*160*64*4 = 163,840
  const size_t OFF_AE    = 3174528;      // 19,660,800
  const size_t OFF_HS16  = 22835328;     // 2*32768*152*4 = 39,845,888
  const size_t OFF_PRE   = 62681216;     // 157,286,400 -> end 219,967,616
  if (ws_size < 219967616ull) return;

  uint32_t* wtih  = (uint32_t*)(ws + OFF_WTIH);
  uint32_t* w2    = (uint32_t*)(ws + OFF_W2);
  float*    bias  = (float*)(ws + OFF_BIAS);
  float*    nums  = (float*)(ws + OFF_NUMS);
  float*    dens  = (float*)(ws + OFF_DENS);
  uint32_t* flags = (uint32_t*)(ws + OFF_FLAGS);
  uint32_t* h2g   = (uint32_t*)(ws + OFF_H2G);
  uint32_t* Ae    = (uint32_t*)(ws + OFF_AE);
  uint32_t* hs16  = (uint32_t*)(ws + OFF_HS16);
  _Float16* pre   = (_Float16*)(ws + OFF_PRE);

  prep_wih<<<dim3((KKP * G4 + 255) / 256, 2), 256, 0, stream>>>(Wihf, Wihb, wtih);
  prep_bias<<<dim3((G4 + 255) / 256), 256, 0, stream>>>(bihf, bhhf, bihb, bhhb, bias);
  prep_w3<<<dim3(2 * NP * 4 * KSTEPS), 64, 0, stream>>>(Whhf, Whhb, w2);
  init_sync<<<dim3(160), 256, 0, stream>>>(flags, h2g);
  gather_emb<<<dim3(MTOT / 64), 256, 0, stream>>>(x, emb, Ae);
  embed_pre_mfma<<<dim3(19, MTOT / 128, 2), 256, 0, stream>>>(Ae, wtih, bias, pre);
  lstm_mfma<<<dim3(NWG), 256, 0, stream>>>(w2, pre, h2g, hs16, flags);
  logits_probs<<<dim3(MTOT / 16), 256, 0, stream>>>(hs16, Wlin, blin, outp);
  crf_num<<<dim3(NB), 256, 0, stream>>>(y, outp, strt, endt, trans, nums);
  crf_alpha<<<dim3(NB), 64, 0, stream>>>(y, outp, strt, endt, trans, dens);
  final_sum<<<1, 64, 0, stream>>>(nums, dens, outp);
}